// Round 1
// baseline (317.840 us; speedup 1.0000x reference)
//
#include <hip/hip_runtime.h>
#include <hip/hip_bf16.h>

#define B_  4
#define T_  1024
#define DM  512
#define H_  8
#define D_  64
#define NTOK (B_*T_)

// workspace float offsets
#define WVEC_OFF   0        // w_phi[128], w_c[128], w_tau[128], {b_phi,b_c,b_tau}@384..386
#define UT_OFF     512      // Ut[48][512]
#define CONST_OFF  25088    // consts[48]
#define S_OFF      25600    // S[4096][48]
#define V_OFF      222208   // V[4096][512]
#define AO_OFF     2319360  // AO[4096][512]
// total 4,416,512 floats = ~17.7 MB

// ---------------------------------------------------------------------------
// Fold the tiny two-layer linear stacks into 128-vectors + scalar biases.
__global__ void k_fold_small(const float* __restrict__ Wphi_in, const float* __restrict__ Wphi_out,
                             const float* __restrict__ bphi_in, const float* __restrict__ bphi_out,
                             const float* __restrict__ Wta, const float* __restrict__ bta,
                             const float* __restrict__ Wtb, const float* __restrict__ btb,
                             const float* __restrict__ Wtau_in, const float* __restrict__ Wtau_out,
                             const float* __restrict__ btau_in, const float* __restrict__ btau_out,
                             float* __restrict__ ws) {
  int i = threadIdx.x; // 128 threads
  float wp = 0.f;
  for (int j = 0; j < 64; ++j) wp += Wphi_in[i*64+j] * Wphi_out[j];
  float wt = 0.f;
  for (int j = 0; j < 32; ++j) wt += Wtau_in[i*32+j] * Wtau_out[j];
  ws[i]       = wp;                    // w_phi
  ws[128 + i] = Wta[i] + Wtb[i];       // w_c  (T_SCALAR == 1 merges t_a,t_b)
  ws[256 + i] = wt;                    // w_tau
  if (i == 0) {
    float bp = bphi_out[0];
    for (int j = 0; j < 64; ++j) bp += bphi_in[j]*Wphi_out[j];
    float bt = btau_out[0];
    for (int j = 0; j < 32; ++j) bt += btau_in[j]*Wtau_out[j];
    ws[384] = bp;                      // b_phi
    ws[385] = bta[0] + btb[0];         // b_c
    ws[386] = bt;                      // b_tau
  }
}

// ---------------------------------------------------------------------------
// Fold per-head Wq/Wk head-slices against the 128-vec halves:
// Ut[s][c], s = h*6 + {0:q_phi,1:q_c,2:q_tau,3:k_phi,4:k_c,5:k_tau}
__global__ void k_fold_U(const float* __restrict__ Wq, const float* __restrict__ bq,
                         const float* __restrict__ Wk, const float* __restrict__ bk,
                         const float* __restrict__ ws,
                         float* __restrict__ Ut, float* __restrict__ consts) {
  int idx = blockIdx.x*256 + threadIdx.x;    // 0..24575
  int c = idx & 511;
  int s = idx >> 9;                          // 0..47
  int h = s / 6, t = s % 6;
  int qk = t / 3;                            // 0 = q-side, 1 = k-side
  int which = t % 3;                         // 0 phi, 1 c, 2 tau
  const float* W = qk ? Wk : Wq;
  const float* wvec = ws + which*128 + qk*64;
  const float* row = W + c*512 + h*64;
  float acc = 0.f;
  #pragma unroll 8
  for (int d = 0; d < 64; ++d) acc += row[d] * wvec[d];
  Ut[s*512 + c] = acc;
  if (c == 0) {
    const float* bb = qk ? bk : bq;
    float cs = 0.f;
    for (int d = 0; d < 64; ++d) cs += bb[h*64+d] * wvec[d];
    if (qk == 0) cs += ws[384 + which];      // pair bias folded into q-side
    consts[s] = cs;
  }
}

// ---------------------------------------------------------------------------
// S[tok][48] = x[tok][:] @ Ut^T + consts
__global__ __launch_bounds__(256) void k_S(const float* __restrict__ x, const float* __restrict__ Ut,
                                           const float* __restrict__ consts, float* __restrict__ S) {
  __shared__ __align__(16) float xs[8][512];
  int row0 = blockIdx.x * 8;
  const float4* xsrc = (const float4*)(x + (size_t)row0*512);
  float4* xdst = (float4*)&xs[0][0];
  #pragma unroll
  for (int l = 0; l < 4; ++l) xdst[threadIdx.x + 256*l] = xsrc[threadIdx.x + 256*l];
  __syncthreads();
  for (int o = threadIdx.x; o < 8*48; o += 256) {
    int r = o / 48, s = o % 48;
    float acc = consts[s];
    const float4* u4 = (const float4*)(Ut + s*512);
    const float4* x4 = (const float4*)&xs[r][0];
    #pragma unroll 4
    for (int c = 0; c < 128; ++c) {
      float4 a = x4[c]; float4 b = u4[c];
      acc = fmaf(a.x,b.x,acc); acc = fmaf(a.y,b.y,acc);
      acc = fmaf(a.z,b.z,acc); acc = fmaf(a.w,b.w,acc);
    }
    S[(size_t)(row0+r)*48 + s] = acc;
  }
}

// ---------------------------------------------------------------------------
// C[4096,512] = A[4096,512] @ W[512,512] + bias  (64x64 tile, 4x4/thread)
__global__ __launch_bounds__(256) void k_gemm64(const float* __restrict__ A, const float* __restrict__ W,
                                                const float* __restrict__ bias, float* __restrict__ C) {
  __shared__ __align__(16) float As[16][64];  // [kk][m]
  __shared__ __align__(16) float Bs[16][64];  // [kk][n]
  int mb = blockIdx.x, nb = blockIdx.y;
  int tid = threadIdx.x;
  int tx = tid & 15, ty = tid >> 4;
  float acc[4][4] = {};
  const float* Ab = A + (size_t)mb*64*512;
  for (int k0 = 0; k0 < 512; k0 += 16) {
    float4 av = *(const float4*)(Ab + (size_t)(tid>>2)*512 + k0 + (tid&3)*4);
    float4 bv = *(const float4*)(W + (size_t)(k0 + (tid>>4))*512 + nb*64 + (tid&15)*4);
    __syncthreads();
    As[(tid&3)*4+0][tid>>2] = av.x;
    As[(tid&3)*4+1][tid>>2] = av.y;
    As[(tid&3)*4+2][tid>>2] = av.z;
    As[(tid&3)*4+3][tid>>2] = av.w;
    *(float4*)&Bs[tid>>4][(tid&15)*4] = bv;
    __syncthreads();
    #pragma unroll
    for (int kk = 0; kk < 16; ++kk) {
      float4 a4 = *(const float4*)&As[kk][ty*4];
      float4 b4 = *(const float4*)&Bs[kk][tx*4];
      acc[0][0] = fmaf(a4.x,b4.x,acc[0][0]); acc[0][1] = fmaf(a4.x,b4.y,acc[0][1]);
      acc[0][2] = fmaf(a4.x,b4.z,acc[0][2]); acc[0][3] = fmaf(a4.x,b4.w,acc[0][3]);
      acc[1][0] = fmaf(a4.y,b4.x,acc[1][0]); acc[1][1] = fmaf(a4.y,b4.y,acc[1][1]);
      acc[1][2] = fmaf(a4.y,b4.z,acc[1][2]); acc[1][3] = fmaf(a4.y,b4.w,acc[1][3]);
      acc[2][0] = fmaf(a4.z,b4.x,acc[2][0]); acc[2][1] = fmaf(a4.z,b4.y,acc[2][1]);
      acc[2][2] = fmaf(a4.z,b4.z,acc[2][2]); acc[2][3] = fmaf(a4.z,b4.w,acc[2][3]);
      acc[3][0] = fmaf(a4.w,b4.x,acc[3][0]); acc[3][1] = fmaf(a4.w,b4.y,acc[3][1]);
      acc[3][2] = fmaf(a4.w,b4.z,acc[3][2]); acc[3][3] = fmaf(a4.w,b4.w,acc[3][3]);
    }
  }
  float4 b4 = *(const float4*)(bias + nb*64 + tx*4);
  #pragma unroll
  for (int i = 0; i < 4; ++i) {
    float4 o;
    o.x = acc[i][0] + b4.x; o.y = acc[i][1] + b4.y;
    o.z = acc[i][2] + b4.z; o.w = acc[i][3] + b4.w;
    *(float4*)(C + (size_t)(mb*64 + ty*4 + i)*512 + nb*64 + tx*4) = o;
  }
}

// ---------------------------------------------------------------------------
// Attention: logits from per-token scalars; softmax (logit in (0,1), no max
// tracking needed); accumulate attn @ V.
// grid (16 q-chunks, 32 bh), block 256 = 4 waves; wave handles 16 q-rows,
// lane = head-dim d.
__global__ __launch_bounds__(256) void k_attn(const float* __restrict__ S, const float* __restrict__ V,
                                              float* __restrict__ AO) {
  __shared__ __align__(16) float Vs[64][64];
  __shared__ __align__(16) float Ew[4][16][64];
  int bh = blockIdx.y;
  int b = bh >> 3, h = bh & 7;
  int tid = threadIdx.x;
  int w = tid >> 6, lane = tid & 63;
  int qrow0 = blockIdx.x*64 + w*16;
  const float* Sb = S + (size_t)b*T_*48 + h*6;

  float sqp[16], sqc[16], sqt[16], acc[16], dsum[16];
  #pragma unroll
  for (int r = 0; r < 16; ++r) {
    const float* p = Sb + (size_t)(qrow0 + r)*48;
    sqp[r] = p[0]; sqc[r] = p[1]; sqt[r] = p[2];
    acc[r] = 0.f; dsum[r] = 0.f;
  }
  const float* Vbh = V + (size_t)b*T_*512 + h*64;

  for (int kb = 0; kb < T_; kb += 64) {
    __syncthreads();  // previous-iter Vs reads done
    #pragma unroll
    for (int l = 0; l < 4; ++l) {
      int idx = tid + 256*l;
      int row = idx >> 4, c4 = idx & 15;
      *(float4*)&Vs[row][c4*4] = *(const float4*)(Vbh + (size_t)(kb+row)*512 + c4*4);
    }
    const float* pk = Sb + (size_t)(kb + lane)*48 + 3;
    float skp = pk[0], skc = pk[1], skt = pk[2];
    __syncthreads();

    #pragma unroll
    for (int r = 0; r < 16; ++r) {
      float aphi = sqp[r] + skp;
      float phi  = 1.f / (1.f + __expf(-aphi));
      float ac   = sqc[r] + skc;
      float ti   = 1.f / (1.f + __expf(-ac));
      float at   = sqt[r] + skt;
      float tau  = fmaxf(at, 0.f) + __logf(1.f + __expf(-fabsf(at))) + 1e-6f;
      float z    = 1.f - __expf(-tau * ti);
      float logit = phi * z / tau;
      float p = __expf(logit);
      Ew[w][r][lane] = p;
      dsum[r] += p;
    }
    __syncthreads();

    #pragma unroll 4
    for (int jj = 0; jj < 16; ++jj) {
      float v0 = Vs[4*jj+0][lane];
      float v1 = Vs[4*jj+1][lane];
      float v2 = Vs[4*jj+2][lane];
      float v3 = Vs[4*jj+3][lane];
      #pragma unroll
      for (int r = 0; r < 16; ++r) {
        float4 e4 = *(const float4*)&Ew[w][r][4*jj];
        acc[r] = fmaf(e4.x, v0, acc[r]);
        acc[r] = fmaf(e4.y, v1, acc[r]);
        acc[r] = fmaf(e4.z, v2, acc[r]);
        acc[r] = fmaf(e4.w, v3, acc[r]);
      }
    }
  }

  #pragma unroll
  for (int r = 0; r < 16; ++r) {
    float s = dsum[r];
    #pragma unroll
    for (int off = 32; off > 0; off >>= 1) s += __shfl_xor(s, off, 64);
    AO[(size_t)(b*T_ + qrow0 + r)*512 + h*64 + lane] = acc[r] / s;
  }
}

// ---------------------------------------------------------------------------
extern "C" void kernel_launch(void* const* d_in, const int* in_sizes, int n_in,
                              void* d_out, int out_size, void* d_ws, size_t ws_size,
                              hipStream_t stream) {
  (void)in_sizes; (void)n_in; (void)out_size; (void)ws_size;
  const float* x        = (const float*)d_in[0];
  const float* Wq       = (const float*)d_in[1];
  const float* bq       = (const float*)d_in[2];
  const float* Wk       = (const float*)d_in[3];
  const float* bk       = (const float*)d_in[4];
  const float* Wv       = (const float*)d_in[5];
  const float* bv       = (const float*)d_in[6];
  const float* Wphi_in  = (const float*)d_in[7];
  const float* bphi_in  = (const float*)d_in[8];
  const float* Wphi_out = (const float*)d_in[9];
  const float* bphi_out = (const float*)d_in[10];
  const float* Wta      = (const float*)d_in[11];
  const float* bta      = (const float*)d_in[12];
  const float* Wtb      = (const float*)d_in[13];
  const float* btb      = (const float*)d_in[14];
  const float* Wtau_in  = (const float*)d_in[15];
  const float* btau_in  = (const float*)d_in[16];
  const float* Wtau_out = (const float*)d_in[17];
  const float* btau_out = (const float*)d_in[18];
  const float* Wo       = (const float*)d_in[19];
  const float* bo       = (const float*)d_in[20];
  float* out = (float*)d_out;
  float* ws  = (float*)d_ws;

  float* wvec   = ws + WVEC_OFF;
  float* Ut     = ws + UT_OFF;
  float* consts = ws + CONST_OFF;
  float* S      = ws + S_OFF;
  float* V      = ws + V_OFF;
  float* AO     = ws + AO_OFF;

  hipLaunchKernelGGL(k_fold_small, dim3(1), dim3(128), 0, stream,
                     Wphi_in, Wphi_out, bphi_in, bphi_out, Wta, bta, Wtb, btb,
                     Wtau_in, Wtau_out, btau_in, btau_out, wvec);
  hipLaunchKernelGGL(k_fold_U, dim3(96), dim3(256), 0, stream,
                     Wq, bq, Wk, bk, wvec, Ut, consts);
  hipLaunchKernelGGL(k_S, dim3(NTOK/8), dim3(256), 0, stream, x, Ut, consts, S);
  hipLaunchKernelGGL(k_gemm64, dim3(NTOK/64, 8), dim3(256), 0, stream, x, Wv, bv, V);
  hipLaunchKernelGGL(k_attn, dim3(T_/64, B_*H_), dim3(256), 0, stream, S, V, AO);
  hipLaunchKernelGGL(k_gemm64, dim3(NTOK/64, 8), dim3(256), 0, stream, AO, Wo, bo, out);
}

// Round 2
// 179.483 us; speedup vs baseline: 1.7709x; 1.7709x over previous
//
#include <hip/hip_runtime.h>
#include <hip/hip_bf16.h>

#define B_  4
#define T_  1024
#define H_  8
#define NTOK (B_*T_)

// workspace float offsets
#define WVEC_OFF   0        // w_phi[128], w_c[128], w_tau[128], {b_phi,b_c,b_tau}@384..386
#define UT_OFF     512      // Ut[48][512]  (pre-scaled by +-log2e)
#define CONST_OFF  25088    // consts[48]   (pre-scaled)
#define S_OFF      25600    // S planes [48][4096]
#define VT_OFF     222208   // VT bf16 [32][64][1024] = 2,097,152 bf16 (1,048,576 float slots)
#define AO_OFF     1270784  // AO fp32 [4096][512]
// total 3,367,936 floats ~= 13.5 MB

#define LOG2E 1.4426950408889634f
#define LN2   0.6931471805599453f

typedef __attribute__((ext_vector_type(4))) float v4f;
typedef __attribute__((ext_vector_type(8))) short v8s;

__device__ inline short bf16r(float f) {
  union { float f; unsigned u; } v; v.f = f;
  return (short)((v.u + 0x7FFFu + ((v.u >> 16) & 1u)) >> 16);
}

// ---------------------------------------------------------------------------
__global__ void k_fold_small(const float* __restrict__ Wphi_in, const float* __restrict__ Wphi_out,
                             const float* __restrict__ bphi_in, const float* __restrict__ bphi_out,
                             const float* __restrict__ Wta, const float* __restrict__ bta,
                             const float* __restrict__ Wtb, const float* __restrict__ btb,
                             const float* __restrict__ Wtau_in, const float* __restrict__ Wtau_out,
                             const float* __restrict__ btau_in, const float* __restrict__ btau_out,
                             float* __restrict__ ws) {
  int i = threadIdx.x; // 128 threads
  float wp = 0.f;
  for (int j = 0; j < 64; ++j) wp += Wphi_in[i*64+j] * Wphi_out[j];
  float wt = 0.f;
  for (int j = 0; j < 32; ++j) wt += Wtau_in[i*32+j] * Wtau_out[j];
  ws[i]       = wp;                    // w_phi
  ws[128 + i] = Wta[i] + Wtb[i];       // w_c  (T_SCALAR == 1)
  ws[256 + i] = wt;                    // w_tau
  if (i == 0) {
    float bp = bphi_out[0];
    for (int j = 0; j < 64; ++j) bp += bphi_in[j]*Wphi_out[j];
    float bt = btau_out[0];
    for (int j = 0; j < 32; ++j) bt += btau_in[j]*Wtau_out[j];
    ws[384] = bp;
    ws[385] = bta[0] + btb[0];
    ws[386] = bt;
  }
}

// ---------------------------------------------------------------------------
// Ut[s][c], s = h*6 + qk*3 + which; pre-scaled: phi,c by -log2e; tau by +log2e
__global__ void k_fold_U(const float* __restrict__ Wq, const float* __restrict__ bq,
                         const float* __restrict__ Wk, const float* __restrict__ bk,
                         const float* __restrict__ ws,
                         float* __restrict__ Ut, float* __restrict__ consts) {
  int idx = blockIdx.x*256 + threadIdx.x;    // 0..24575
  int c = idx & 511;
  int s = idx >> 9;                          // 0..47
  int h = s / 6, t = s % 6;
  int qk = t / 3;
  int which = t % 3;
  float scale = (which == 2) ? LOG2E : -LOG2E;
  const float* W = qk ? Wk : Wq;
  const float* wvec = ws + which*128 + qk*64;
  const float* row = W + c*512 + h*64;
  float acc = 0.f;
  #pragma unroll 8
  for (int d = 0; d < 64; ++d) acc += row[d] * wvec[d];
  Ut[s*512 + c] = acc * scale;
  if (c == 0) {
    const float* bb = qk ? bk : bq;
    float cs = 0.f;
    for (int d = 0; d < 64; ++d) cs += bb[h*64+d] * wvec[d];
    if (qk == 0) cs += ws[384 + which];
    consts[s] = cs * scale;
  }
}

// ---------------------------------------------------------------------------
// S planes: S[s][tok] = x[tok] . Ut[s] + consts[s]
__global__ __launch_bounds__(256) void k_S(const float* __restrict__ x, const float* __restrict__ Ut,
                                           const float* __restrict__ consts, float* __restrict__ S) {
  __shared__ __align__(16) float xs[8][512];
  int row0 = blockIdx.x * 8;
  const float4* xsrc = (const float4*)(x + (size_t)row0*512);
  float4* xdst = (float4*)&xs[0][0];
  #pragma unroll
  for (int l = 0; l < 4; ++l) xdst[threadIdx.x + 256*l] = xsrc[threadIdx.x + 256*l];
  __syncthreads();
  for (int o = threadIdx.x; o < 8*48; o += 256) {
    int r = o / 48, s = o % 48;
    float acc = consts[s];
    const float4* u4 = (const float4*)(Ut + s*512);
    const float4* x4 = (const float4*)&xs[r][0];
    #pragma unroll 4
    for (int c = 0; c < 128; ++c) {
      float4 a = x4[c]; float4 b = u4[c];
      acc = fmaf(a.x,b.x,acc); acc = fmaf(a.y,b.y,acc);
      acc = fmaf(a.z,b.z,acc); acc = fmaf(a.w,b.w,acc);
    }
    S[(size_t)s*NTOK + row0 + r] = acc;
  }
}

// ---------------------------------------------------------------------------
// C[4096,512] = A[4096,512] @ W[512,512] + bias.
// WRITE_VT: instead of fp32 C, write transposed bf16 VT[b*8+h][d][t].
template<bool WRITE_VT>
__global__ __launch_bounds__(256) void k_gemm64(const float* __restrict__ A, const float* __restrict__ W,
                                                const float* __restrict__ bias, float* __restrict__ C,
                                                __hip_bfloat16* __restrict__ VT) {
  __shared__ __align__(16) float As[16][64];
  __shared__ __align__(16) float Bs[16][64];
  int mb = blockIdx.x, nb = blockIdx.y;
  int tid = threadIdx.x;
  int tx = tid & 15, ty = tid >> 4;
  float acc[4][4] = {};
  const float* Ab = A + (size_t)mb*64*512;
  for (int k0 = 0; k0 < 512; k0 += 16) {
    float4 av = *(const float4*)(Ab + (size_t)(tid>>2)*512 + k0 + (tid&3)*4);
    float4 bv = *(const float4*)(W + (size_t)(k0 + (tid>>4))*512 + nb*64 + (tid&15)*4);
    __syncthreads();
    As[(tid&3)*4+0][tid>>2] = av.x;
    As[(tid&3)*4+1][tid>>2] = av.y;
    As[(tid&3)*4+2][tid>>2] = av.z;
    As[(tid&3)*4+3][tid>>2] = av.w;
    *(float4*)&Bs[tid>>4][(tid&15)*4] = bv;
    __syncthreads();
    #pragma unroll
    for (int kk = 0; kk < 16; ++kk) {
      float4 a4 = *(const float4*)&As[kk][ty*4];
      float4 b4 = *(const float4*)&Bs[kk][tx*4];
      acc[0][0] = fmaf(a4.x,b4.x,acc[0][0]); acc[0][1] = fmaf(a4.x,b4.y,acc[0][1]);
      acc[0][2] = fmaf(a4.x,b4.z,acc[0][2]); acc[0][3] = fmaf(a4.x,b4.w,acc[0][3]);
      acc[1][0] = fmaf(a4.y,b4.x,acc[1][0]); acc[1][1] = fmaf(a4.y,b4.y,acc[1][1]);
      acc[1][2] = fmaf(a4.y,b4.z,acc[1][2]); acc[1][3] = fmaf(a4.y,b4.w,acc[1][3]);
      acc[2][0] = fmaf(a4.z,b4.x,acc[2][0]); acc[2][1] = fmaf(a4.z,b4.y,acc[2][1]);
      acc[2][2] = fmaf(a4.z,b4.z,acc[2][2]); acc[2][3] = fmaf(a4.z,b4.w,acc[2][3]);
      acc[3][0] = fmaf(a4.w,b4.x,acc[3][0]); acc[3][1] = fmaf(a4.w,b4.y,acc[3][1]);
      acc[3][2] = fmaf(a4.w,b4.z,acc[3][2]); acc[3][3] = fmaf(a4.w,b4.w,acc[3][3]);
    }
  }
  float4 b4 = *(const float4*)(bias + nb*64 + tx*4);
  if constexpr (WRITE_VT) {
    __shared__ __align__(16) float tile[64][65];
    #pragma unroll
    for (int i = 0; i < 4; ++i) {
      tile[ty*4+i][tx*4+0] = acc[i][0] + b4.x;
      tile[ty*4+i][tx*4+1] = acc[i][1] + b4.y;
      tile[ty*4+i][tx*4+2] = acc[i][2] + b4.z;
      tile[ty*4+i][tx*4+3] = acc[i][3] + b4.w;
    }
    __syncthreads();
    int d = tid >> 2;            // 0..63 (col of this tile = head dim)
    int c0 = (tid & 3) * 16;     // t-chunk within tile
    v8s o0, o1;
    #pragma unroll
    for (int jj = 0; jj < 8; ++jj) {
      o0[jj] = bf16r(tile[c0+jj][d]);
      o1[jj] = bf16r(tile[c0+8+jj][d]);
    }
    int b = mb >> 4, h = nb;
    size_t base = ((size_t)((b*8 + h)*64 + d))*1024 + (mb & 15)*64 + c0;
    *(v8s*)(VT + base)     = o0;
    *(v8s*)(VT + base + 8) = o1;
  } else {
    #pragma unroll
    for (int i = 0; i < 4; ++i) {
      float4 o;
      o.x = acc[i][0] + b4.x; o.y = acc[i][1] + b4.y;
      o.z = acc[i][2] + b4.z; o.w = acc[i][3] + b4.w;
      *(float4*)(C + (size_t)(mb*64 + ty*4 + i)*512 + nb*64 + tx*4) = o;
    }
  }
}

// ---------------------------------------------------------------------------
// MFMA flash attention: 1 wave per (16 q-rows, b, h); no LDS, no barriers.
// A-frag (16x16x32 bf16): lane l -> q-row l&15, k = 8*(l>>4)+j (j=0..7).
// B-frag: lane l -> d-col (tile*16 + (l&15)), k = 8*(l>>4)+j  == VT row read.
// C: col = lane&15, row = (lane>>4)*4 + reg  (m89-verified).
__global__ __launch_bounds__(64) void k_attn(const float* __restrict__ S,
                                             const __hip_bfloat16* __restrict__ VT,
                                             float* __restrict__ AO) {
  int bh = blockIdx.y;
  int b = bh >> 3, h = bh & 7;
  int q0 = blockIdx.x * 16;
  int l = threadIdx.x;
  int ra = l & 15, kg = l >> 4;

  const float* Sq0 = S + (size_t)(h*6+0)*NTOK + b*T_;
  const float* Sq1 = S + (size_t)(h*6+1)*NTOK + b*T_;
  const float* Sq2 = S + (size_t)(h*6+2)*NTOK + b*T_;
  const float* Sk0 = S + (size_t)(h*6+3)*NTOK + b*T_;
  const float* Sk1 = S + (size_t)(h*6+4)*NTOK + b*T_;
  const float* Sk2 = S + (size_t)(h*6+5)*NTOK + b*T_;
  float qp = Sq0[q0+ra], qc = Sq1[q0+ra], qt = Sq2[q0+ra];
  const __hip_bfloat16* Vb = VT + (size_t)bh*64*1024;

  v4f acc0 = {0.f,0.f,0.f,0.f}, acc1 = acc0, acc2 = acc0, acc3 = acc0, dacc = acc0;
  v8s ones;
  #pragma unroll
  for (int j = 0; j < 8; ++j) ones[j] = (short)0x3F80;   // bf16(1.0)

  for (int k0 = 0; k0 < T_; k0 += 32) {
    int kk = k0 + kg*8;
    v4f kp0 = *(const v4f*)&Sk0[kk], kp1 = *(const v4f*)&Sk0[kk+4];
    v4f kc0 = *(const v4f*)&Sk1[kk], kc1 = *(const v4f*)&Sk1[kk+4];
    v4f kt0 = *(const v4f*)&Sk2[kk], kt1 = *(const v4f*)&Sk2[kk+4];
    v8s afrag;
    #pragma unroll
    for (int j = 0; j < 8; ++j) {
      float kp = (j < 4) ? kp0[j] : kp1[j-4];
      float kc = (j < 4) ? kc0[j] : kc1[j-4];
      float kt = (j < 4) ? kt0[j] : kt1[j-4];
      float ephi = __builtin_amdgcn_exp2f(qp + kp);            // e^{-a_phi}
      float ec   = __builtin_amdgcn_exp2f(qc + kc);            // e^{-a_c}
      float ti   = __builtin_amdgcn_rcpf(1.f + ec);            // sigmoid(a_c)
      float g    = __builtin_amdgcn_exp2f(qt + kt);            // e^{a_tau}
      float tau  = fmaf(__builtin_amdgcn_logf(1.f + g), LN2, 1e-6f); // softplus + eps
      float z    = 1.f - __builtin_amdgcn_exp2f(tau * ti * (-LOG2E));
      float pot  = __builtin_amdgcn_rcpf((1.f + ephi) * tau);  // phi / tau
      float p    = __builtin_amdgcn_exp2f(z * pot * LOG2E);    // exp(logit)
      afrag[j] = bf16r(p);
    }
    const __hip_bfloat16* vb = Vb + (size_t)ra*1024 + kk;
    v8s b0 = *(const v8s*)(vb);
    v8s b1 = *(const v8s*)(vb + 16*1024);
    v8s b2 = *(const v8s*)(vb + 32*1024);
    v8s b3 = *(const v8s*)(vb + 48*1024);
    acc0 = __builtin_amdgcn_mfma_f32_16x16x32_bf16(afrag, b0, acc0, 0, 0, 0);
    acc1 = __builtin_amdgcn_mfma_f32_16x16x32_bf16(afrag, b1, acc1, 0, 0, 0);
    acc2 = __builtin_amdgcn_mfma_f32_16x16x32_bf16(afrag, b2, acc2, 0, 0, 0);
    acc3 = __builtin_amdgcn_mfma_f32_16x16x32_bf16(afrag, b3, acc3, 0, 0, 0);
    dacc = __builtin_amdgcn_mfma_f32_16x16x32_bf16(afrag, ones, dacc, 0, 0, 0);
  }

  // dsum for C-row (kg*4+reg) lives in lane (l&48), any col (use col 0 lanes' value)
  float ds[4];
  #pragma unroll
  for (int r = 0; r < 4; ++r) ds[r] = __shfl(dacc[r], l & 48, 64);

  size_t obase = ((size_t)(b*T_ + q0 + kg*4))*512 + h*64 + ra;
  #pragma unroll
  for (int r = 0; r < 4; ++r) {
    size_t o = obase + (size_t)r*512;
    AO[o +  0] = acc0[r] / ds[r];
    AO[o + 16] = acc1[r] / ds[r];
    AO[o + 32] = acc2[r] / ds[r];
    AO[o + 48] = acc3[r] / ds[r];
  }
}

// ---------------------------------------------------------------------------
extern "C" void kernel_launch(void* const* d_in, const int* in_sizes, int n_in,
                              void* d_out, int out_size, void* d_ws, size_t ws_size,
                              hipStream_t stream) {
  (void)in_sizes; (void)n_in; (void)out_size; (void)ws_size;
  const float* x        = (const float*)d_in[0];
  const float* Wq       = (const float*)d_in[1];
  const float* bq       = (const float*)d_in[2];
  const float* Wk       = (const float*)d_in[3];
  const float* bk       = (const float*)d_in[4];
  const float* Wv       = (const float*)d_in[5];
  const float* bv       = (const float*)d_in[6];
  const float* Wphi_in  = (const float*)d_in[7];
  const float* bphi_in  = (const float*)d_in[8];
  const float* Wphi_out = (const float*)d_in[9];
  const float* bphi_out = (const float*)d_in[10];
  const float* Wta      = (const float*)d_in[11];
  const float* bta      = (const float*)d_in[12];
  const float* Wtb      = (const float*)d_in[13];
  const float* btb      = (const float*)d_in[14];
  const float* Wtau_in  = (const float*)d_in[15];
  const float* btau_in  = (const float*)d_in[16];
  const float* Wtau_out = (const float*)d_in[17];
  const float* btau_out = (const float*)d_in[18];
  const float* Wo       = (const float*)d_in[19];
  const float* bo       = (const float*)d_in[20];
  float* out = (float*)d_out;
  float* ws  = (float*)d_ws;

  float* wvec   = ws + WVEC_OFF;
  float* Ut     = ws + UT_OFF;
  float* consts = ws + CONST_OFF;
  float* S      = ws + S_OFF;
  __hip_bfloat16* VT = (__hip_bfloat16*)(ws + VT_OFF);
  float* AO     = ws + AO_OFF;

  hipLaunchKernelGGL(k_fold_small, dim3(1), dim3(128), 0, stream,
                     Wphi_in, Wphi_out, bphi_in, bphi_out, Wta, bta, Wtb, btb,
                     Wtau_in, Wtau_out, btau_in, btau_out, wvec);
  hipLaunchKernelGGL(k_fold_U, dim3(96), dim3(256), 0, stream,
                     Wq, bq, Wk, bk, wvec, Ut, consts);
  hipLaunchKernelGGL(k_S, dim3(NTOK/8), dim3(256), 0, stream, x, Ut, consts, S);
  k_gemm64<true><<<dim3(NTOK/64, 8), dim3(256), 0, stream>>>(x, Wv, bv, nullptr, VT);
  k_attn<<<dim3(T_/16, B_*H_), dim3(64), 0, stream>>>(S, VT, AO);
  k_gemm64<false><<<dim3(NTOK/64, 8), dim3(256), 0, stream>>>(AO, Wo, bo, out, nullptr);
}

// Round 3
// 101.770 us; speedup vs baseline: 3.1231x; 1.7636x over previous
//
#include <hip/hip_runtime.h>
#include <hip/hip_bf16.h>

#define B_  4
#define T_  1024
#define H_  8
#define NTOK (B_*T_)

// workspace float offsets
#define WVEC_OFF  0         // 512
#define CONST_OFF 512       // 48 (+pad)
#define UTH_OFF   576       // 48x512 bf16 = 12288 float slots
#define UTL_OFF   12864     // 12288
#define XHI_OFF   25152     // 4096x512 bf16 = 1048576 float slots   (aliased by AOh)
#define XLO_OFF   1073728   // 1048576                                (aliased by AOl)
#define WVTH_OFF  2122304   // 512x512 bf16 = 131072 float slots
#define WVTL_OFF  2253376
#define WOTH_OFF  2384448
#define WOTL_OFF  2515520
#define S_OFF     2646592   // 48x4096 fp32 = 196608
#define VT_OFF    2843200   // 32x64x1024 bf16 = 1048576
// end 3,891,776 floats ~= 15.6 MB

#define LOG2E 1.4426950408889634f
#define LN2   0.6931471805599453f

typedef __attribute__((ext_vector_type(4))) float v4f;
typedef __attribute__((ext_vector_type(8))) short v8s;

__device__ inline short bf16r(float f) {
  union { float f; unsigned u; } v; v.f = f;
  return (short)((v.u + 0x7FFFu + ((v.u >> 16) & 1u)) >> 16);
}
__device__ inline float bf16f(short s) {
  union { unsigned u; float f; } v; v.u = ((unsigned)(unsigned short)s) << 16; return v.f;
}

// ---------------------------------------------------------------------------
__global__ void k_fold_small(const float* __restrict__ Wphi_in, const float* __restrict__ Wphi_out,
                             const float* __restrict__ bphi_in, const float* __restrict__ bphi_out,
                             const float* __restrict__ Wta, const float* __restrict__ bta,
                             const float* __restrict__ Wtb, const float* __restrict__ btb,
                             const float* __restrict__ Wtau_in, const float* __restrict__ Wtau_out,
                             const float* __restrict__ btau_in, const float* __restrict__ btau_out,
                             float* __restrict__ ws) {
  int i = threadIdx.x; // 128
  float wp = 0.f;
  for (int j = 0; j < 64; ++j) wp += Wphi_in[i*64+j] * Wphi_out[j];
  float wt = 0.f;
  for (int j = 0; j < 32; ++j) wt += Wtau_in[i*32+j] * Wtau_out[j];
  ws[i]       = wp;
  ws[128 + i] = Wta[i] + Wtb[i];       // T_SCALAR == 1
  ws[256 + i] = wt;
  if (i == 0) {
    float bp = bphi_out[0];
    for (int j = 0; j < 64; ++j) bp += bphi_in[j]*Wphi_out[j];
    float bt = btau_out[0];
    for (int j = 0; j < 32; ++j) bt += btau_in[j]*Wtau_out[j];
    ws[384] = bp;
    ws[385] = bta[0] + btb[0];
    ws[386] = bt;
  }
}

// ---------------------------------------------------------------------------
// Ut hi/lo bf16 [48][512]; s = h*6 + qk*3 + which; phi,c scaled -log2e; tau +log2e
__global__ void k_fold_U(const float* __restrict__ Wq, const float* __restrict__ bq,
                         const float* __restrict__ Wk, const float* __restrict__ bk,
                         const float* __restrict__ ws,
                         short* __restrict__ Uth, short* __restrict__ Utl,
                         float* __restrict__ consts) {
  int idx = blockIdx.x*256 + threadIdx.x;    // 0..24575
  int c = idx & 511;
  int s = idx >> 9;
  int h = s / 6, t = s % 6;
  int qk = t / 3;
  int which = t % 3;
  float scale = (which == 2) ? LOG2E : -LOG2E;
  const float* W = qk ? Wk : Wq;
  const float* wvec = ws + which*128 + qk*64;
  const float* row = W + c*512 + h*64;
  float acc = 0.f;
  #pragma unroll 8
  for (int d = 0; d < 64; ++d) acc += row[d] * wvec[d];
  float v = acc * scale;
  short hi = bf16r(v);
  Uth[s*512 + c] = hi;
  Utl[s*512 + c] = bf16r(v - bf16f(hi));
  if (c == 0) {
    const float* bb = qk ? bk : bq;
    float cs = 0.f;
    for (int d = 0; d < 64; ++d) cs += bb[h*64+d] * wvec[d];
    if (qk == 0) cs += ws[384 + which];
    consts[s] = cs * scale;
  }
}

// ---------------------------------------------------------------------------
// fp32 -> bf16 hi/lo split, 8 elems/thread
__global__ __launch_bounds__(256) void k_split_x(const float* __restrict__ x,
                                                 short* __restrict__ xh, short* __restrict__ xl) {
  size_t i = (size_t)(blockIdx.x*256 + threadIdx.x) * 8;
  float4 a = *(const float4*)(x + i);
  float4 b = *(const float4*)(x + i + 4);
  float vals[8] = {a.x,a.y,a.z,a.w,b.x,b.y,b.z,b.w};
  v8s hi, lo;
  #pragma unroll
  for (int j = 0; j < 8; ++j) {
    short h = bf16r(vals[j]);
    hi[j] = h;
    lo[j] = bf16r(vals[j] - bf16f(h));
  }
  *(v8s*)(xh + i) = hi;
  *(v8s*)(xl + i) = lo;
}

// ---------------------------------------------------------------------------
// Transpose + split W[512k][512n] -> Wt hi/lo [512n][512k]; z selects Wv/Wo
__global__ __launch_bounds__(256) void k_split_w(const float* __restrict__ Wv, const float* __restrict__ Wo,
                                                 short* __restrict__ Wvh, short* __restrict__ Wvl,
                                                 short* __restrict__ Woh, short* __restrict__ Wol) {
  __shared__ float tile[64][65];
  int k0 = blockIdx.x*64, n0 = blockIdx.y*64;
  const float* src = blockIdx.z ? Wo : Wv;
  short* dh = blockIdx.z ? Woh : Wvh;
  short* dl = blockIdx.z ? Wol : Wvl;
  int t = threadIdx.x;
  int kr = t >> 2, cq = t & 3;
  #pragma unroll
  for (int i = 0; i < 4; ++i) {
    float4 v = *(const float4*)(src + (size_t)(k0+kr)*512 + n0 + cq*16 + i*4);
    tile[kr][cq*16+i*4+0] = v.x; tile[kr][cq*16+i*4+1] = v.y;
    tile[kr][cq*16+i*4+2] = v.z; tile[kr][cq*16+i*4+3] = v.w;
  }
  __syncthreads();
  int nr = t >> 2, ko = t & 3;
  v8s h0,h1,l0,l1;
  #pragma unroll
  for (int i = 0; i < 8; ++i) {
    float a = tile[ko*16+i][nr];
    float b = tile[ko*16+8+i][nr];
    short ha = bf16r(a), hb = bf16r(b);
    h0[i] = ha; l0[i] = bf16r(a - bf16f(ha));
    h1[i] = hb; l1[i] = bf16r(b - bf16f(hb));
  }
  size_t base = (size_t)(n0+nr)*512 + k0 + ko*16;
  *(v8s*)(dh + base) = h0; *(v8s*)(dh + base + 8) = h1;
  *(v8s*)(dl + base) = l0; *(v8s*)(dl + base + 8) = l1;
}

// ---------------------------------------------------------------------------
// S[s][tok] = split-bf16 MFMA of x @ Ut^T + consts. 256 blocks x 16 rows;
// 4 waves split K (128 each), LDS combine.
__global__ __launch_bounds__(256) void k_S(const short* __restrict__ xh, const short* __restrict__ xl,
                                           const short* __restrict__ Uth, const short* __restrict__ Utl,
                                           const float* __restrict__ consts, float* __restrict__ S) {
  __shared__ float red[3][64][12];
  int tid = threadIdx.x, w = tid >> 6, l = tid & 63, ra = l & 15, kg = l >> 4;
  int mb = blockIdx.x;
  v4f acc[3] = {{0,0,0,0},{0,0,0,0},{0,0,0,0}};
  const short* xa = xh + (size_t)(mb*16+ra)*512;
  const short* xb = xl + (size_t)(mb*16+ra)*512;
  #pragma unroll
  for (int ks = 0; ks < 4; ++ks) {
    int kk = w*128 + ks*32 + kg*8;
    v8s ah = *(const v8s*)(xa + kk);
    v8s al = *(const v8s*)(xb + kk);
    #pragma unroll
    for (int nf = 0; nf < 3; ++nf) {
      v8s bh = *(const v8s*)(Uth + (size_t)(nf*16+ra)*512 + kk);
      v8s bl = *(const v8s*)(Utl + (size_t)(nf*16+ra)*512 + kk);
      acc[nf] = __builtin_amdgcn_mfma_f32_16x16x32_bf16(ah, bh, acc[nf], 0, 0, 0);
      acc[nf] = __builtin_amdgcn_mfma_f32_16x16x32_bf16(ah, bl, acc[nf], 0, 0, 0);
      acc[nf] = __builtin_amdgcn_mfma_f32_16x16x32_bf16(al, bh, acc[nf], 0, 0, 0);
    }
  }
  if (w > 0) {
    #pragma unroll
    for (int nf = 0; nf < 3; ++nf) *(v4f*)&red[w-1][l][nf*4] = acc[nf];
  }
  __syncthreads();
  if (w == 0) {
    #pragma unroll
    for (int p = 0; p < 3; ++p)
      #pragma unroll
      for (int nf = 0; nf < 3; ++nf) acc[nf] += *(const v4f*)&red[p][l][nf*4];
    int t0 = mb*16 + kg*4;
    #pragma unroll
    for (int nf = 0; nf < 3; ++nf) {
      int s = nf*16 + ra;
      v4f o = acc[nf] + consts[s];
      *(v4f*)(S + (size_t)s*NTOK + t0) = o;
    }
  }
}

// ---------------------------------------------------------------------------
// Split-bf16 MFMA GEMM: C[4096,512] = A @ W + bias, via Ah*Wh + Ah*Wl + Al*Wh.
// A row-major bf16 [4096][512]; B = Wt [512 n][512 k] bf16.
// MODE 0: fp32 C + bias.  MODE 1: bf16 VT[b*8+h][d][t] (BN=64 = one head).
template<int MODE>
__global__ __launch_bounds__(256) void k_gemm(const short* __restrict__ Ah, const short* __restrict__ Al,
                                              const short* __restrict__ Bh, const short* __restrict__ Bl,
                                              const float* __restrict__ bias,
                                              float* __restrict__ C, short* __restrict__ VT) {
  __shared__ short As_h[64][40], As_l[64][40], Bs_h[64][40], Bs_l[64][40];
  int tid = threadIdx.x, w = tid >> 6, l = tid & 63, ra = l & 15, kg = l >> 4;
  int wr = w >> 1, wc = w & 1;
  int mb = blockIdx.x, nb = blockIdx.y;
  v4f acc[2][2] = {};
  int srow = tid >> 2, soct = tid & 3;
  const short* gAh = Ah + (size_t)(mb*64+srow)*512 + soct*8;
  const short* gAl = Al + (size_t)(mb*64+srow)*512 + soct*8;
  const short* gBh = Bh + (size_t)(nb*64+srow)*512 + soct*8;
  const short* gBl = Bl + (size_t)(nb*64+srow)*512 + soct*8;
  for (int k0 = 0; k0 < 512; k0 += 32) {
    v8s sa = *(const v8s*)(gAh + k0);
    v8s sb = *(const v8s*)(gAl + k0);
    v8s sc = *(const v8s*)(gBh + k0);
    v8s sd = *(const v8s*)(gBl + k0);
    __syncthreads();
    *(v8s*)&As_h[srow][soct*8] = sa;
    *(v8s*)&As_l[srow][soct*8] = sb;
    *(v8s*)&Bs_h[srow][soct*8] = sc;
    *(v8s*)&Bs_l[srow][soct*8] = sd;
    __syncthreads();
    v8s ah[2], al[2], bh[2], bl[2];
    #pragma unroll
    for (int mi = 0; mi < 2; ++mi) {
      int r = wr*32 + mi*16 + ra;
      ah[mi] = *(const v8s*)&As_h[r][kg*8];
      al[mi] = *(const v8s*)&As_l[r][kg*8];
    }
    #pragma unroll
    for (int ni = 0; ni < 2; ++ni) {
      int r = wc*32 + ni*16 + ra;
      bh[ni] = *(const v8s*)&Bs_h[r][kg*8];
      bl[ni] = *(const v8s*)&Bs_l[r][kg*8];
    }
    #pragma unroll
    for (int mi = 0; mi < 2; ++mi)
      #pragma unroll
      for (int ni = 0; ni < 2; ++ni) {
        acc[mi][ni] = __builtin_amdgcn_mfma_f32_16x16x32_bf16(ah[mi], bh[ni], acc[mi][ni], 0, 0, 0);
        acc[mi][ni] = __builtin_amdgcn_mfma_f32_16x16x32_bf16(ah[mi], bl[ni], acc[mi][ni], 0, 0, 0);
        acc[mi][ni] = __builtin_amdgcn_mfma_f32_16x16x32_bf16(al[mi], bh[ni], acc[mi][ni], 0, 0, 0);
      }
  }
  if constexpr (MODE == 0) {
    #pragma unroll
    for (int ni = 0; ni < 2; ++ni) {
      int n = nb*64 + wc*32 + ni*16 + ra;
      float bv_ = bias[n];
      #pragma unroll
      for (int mi = 0; mi < 2; ++mi) {
        int row = mb*64 + wr*32 + mi*16 + kg*4;
        #pragma unroll
        for (int r = 0; r < 4; ++r)
          C[(size_t)(row+r)*512 + n] = acc[mi][ni][r] + bv_;
      }
    }
  } else {
    __shared__ float ldsT[64][65];
    #pragma unroll
    for (int ni = 0; ni < 2; ++ni) {
      int lc = wc*32 + ni*16 + ra;
      float bv_ = bias[nb*64 + lc];
      #pragma unroll
      for (int mi = 0; mi < 2; ++mi) {
        int lr = wr*32 + mi*16 + kg*4;
        #pragma unroll
        for (int r = 0; r < 4; ++r)
          ldsT[lc][lr+r] = acc[mi][ni][r] + bv_;
      }
    }
    __syncthreads();
    int d = tid >> 2, tq = tid & 3;
    v8s h0, h1;
    #pragma unroll
    for (int i = 0; i < 8; ++i) {
      h0[i] = bf16r(ldsT[d][tq*16+i]);
      h1[i] = bf16r(ldsT[d][tq*16+8+i]);
    }
    size_t base = ((size_t)(((mb>>4)*8 + nb)*64 + d))*1024 + (mb&15)*64 + tq*16;
    *(v8s*)(VT + base)     = h0;
    *(v8s*)(VT + base + 8) = h1;
  }
}

// ---------------------------------------------------------------------------
// MFMA flash attention, split-K x4 (4 waves/block), LDS combine.
// Emits AO as bf16 hi/lo planes for the split-bf16 output GEMM.
__global__ __launch_bounds__(256) void k_attn(const float* __restrict__ S,
                                              const short* __restrict__ VT,
                                              short* __restrict__ AOh, short* __restrict__ AOl) {
  __shared__ float red[3][64][20];
  int tid = threadIdx.x, w = tid >> 6, l = tid & 63, ra = l & 15, kg = l >> 4;
  int bh = blockIdx.y, b = bh >> 3, h = bh & 7;
  int q0 = blockIdx.x * 16;
  const float* Sb = S + (size_t)h*6*NTOK + b*T_;
  float qp = Sb[q0+ra], qc = Sb[NTOK + q0+ra], qt = Sb[2*NTOK + q0+ra];
  const float* Skp = Sb + 3*NTOK;
  const float* Skc = Sb + 4*NTOK;
  const float* Skt = Sb + 5*NTOK;
  const short* Vb = VT + (size_t)bh*64*1024 + (size_t)ra*1024;

  v4f acc0 = {0.f,0.f,0.f,0.f}, acc1 = acc0, acc2 = acc0, acc3 = acc0, dacc = acc0;
  v8s ones;
  #pragma unroll
  for (int j = 0; j < 8; ++j) ones[j] = (short)0x3F80;

  for (int k0 = w*256; k0 < w*256 + 256; k0 += 32) {
    int kk = k0 + kg*8;
    v4f kp0 = *(const v4f*)&Skp[kk], kp1 = *(const v4f*)&Skp[kk+4];
    v4f kc0 = *(const v4f*)&Skc[kk], kc1 = *(const v4f*)&Skc[kk+4];
    v4f kt0 = *(const v4f*)&Skt[kk], kt1 = *(const v4f*)&Skt[kk+4];
    v8s afrag;
    #pragma unroll
    for (int j = 0; j < 8; ++j) {
      float kp = (j < 4) ? kp0[j] : kp1[j-4];
      float kc = (j < 4) ? kc0[j] : kc1[j-4];
      float kt = (j < 4) ? kt0[j] : kt1[j-4];
      float ephi = __builtin_amdgcn_exp2f(qp + kp);            // e^{-a_phi}
      float ec   = __builtin_amdgcn_exp2f(qc + kc);            // e^{-a_c}
      float ti   = __builtin_amdgcn_rcpf(1.f + ec);            // sigmoid(a_c)
      float g    = __builtin_amdgcn_exp2f(qt + kt);            // e^{a_tau}
      float t2   = __builtin_amdgcn_logf(1.f + g);             // softplus/ln2
      float z    = 1.f - __builtin_amdgcn_exp2f(-t2 * ti);
      float tau  = fmaf(t2, LN2, 1e-6f);
      float pot  = __builtin_amdgcn_rcpf((1.f + ephi) * tau);  // phi / tau
      float p    = __builtin_amdgcn_exp2f(z * pot * LOG2E);    // exp(logit)
      afrag[j] = bf16r(p);
    }
    v8s b0 = *(const v8s*)(Vb + kk);
    v8s b1 = *(const v8s*)(Vb + 16*1024 + kk);
    v8s b2 = *(const v8s*)(Vb + 32*1024 + kk);
    v8s b3 = *(const v8s*)(Vb + 48*1024 + kk);
    acc0 = __builtin_amdgcn_mfma_f32_16x16x32_bf16(afrag, b0, acc0, 0, 0, 0);
    acc1 = __builtin_amdgcn_mfma_f32_16x16x32_bf16(afrag, b1, acc1, 0, 0, 0);
    acc2 = __builtin_amdgcn_mfma_f32_16x16x32_bf16(afrag, b2, acc2, 0, 0, 0);
    acc3 = __builtin_amdgcn_mfma_f32_16x16x32_bf16(afrag, b3, acc3, 0, 0, 0);
    dacc = __builtin_amdgcn_mfma_f32_16x16x32_bf16(afrag, ones, dacc, 0, 0, 0);
  }

  if (w > 0) {
    float* rp = &red[w-1][l][0];
    *(v4f*)(rp)      = acc0;
    *(v4f*)(rp + 4)  = acc1;
    *(v4f*)(rp + 8)  = acc2;
    *(v4f*)(rp + 12) = acc3;
    *(v4f*)(rp + 16) = dacc;
  }
  __syncthreads();
  if (w == 0) {
    #pragma unroll
    for (int p = 0; p < 3; ++p) {
      const float* rp = &red[p][l][0];
      acc0 += *(const v4f*)(rp);
      acc1 += *(const v4f*)(rp + 4);
      acc2 += *(const v4f*)(rp + 8);
      acc3 += *(const v4f*)(rp + 12);
      dacc += *(const v4f*)(rp + 16);
    }
    size_t obase = ((size_t)(b*T_ + q0 + kg*4))*512 + h*64 + ra;
    #pragma unroll
    for (int r = 0; r < 4; ++r) {
      float inv = __builtin_amdgcn_rcpf(dacc[r]);
      size_t o = obase + (size_t)r*512;
      float v0 = acc0[r]*inv, v1 = acc1[r]*inv, v2 = acc2[r]*inv, v3 = acc3[r]*inv;
      short h0 = bf16r(v0), h1 = bf16r(v1), h2 = bf16r(v2), h3 = bf16r(v3);
      AOh[o+0]  = h0; AOl[o+0]  = bf16r(v0 - bf16f(h0));
      AOh[o+16] = h1; AOl[o+16] = bf16r(v1 - bf16f(h1));
      AOh[o+32] = h2; AOl[o+32] = bf16r(v2 - bf16f(h2));
      AOh[o+48] = h3; AOl[o+48] = bf16r(v3 - bf16f(h3));
    }
  }
}

// ---------------------------------------------------------------------------
extern "C" void kernel_launch(void* const* d_in, const int* in_sizes, int n_in,
                              void* d_out, int out_size, void* d_ws, size_t ws_size,
                              hipStream_t stream) {
  (void)in_sizes; (void)n_in; (void)out_size; (void)ws_size;
  const float* x        = (const float*)d_in[0];
  const float* Wq       = (const float*)d_in[1];
  const float* bq       = (const float*)d_in[2];
  const float* Wk       = (const float*)d_in[3];
  const float* bk       = (const float*)d_in[4];
  const float* Wv       = (const float*)d_in[5];
  const float* bv       = (const float*)d_in[6];
  const float* Wphi_in  = (const float*)d_in[7];
  const float* bphi_in  = (const float*)d_in[8];
  const float* Wphi_out = (const float*)d_in[9];
  const float* bphi_out = (const float*)d_in[10];
  const float* Wta      = (const float*)d_in[11];
  const float* bta      = (const float*)d_in[12];
  const float* Wtb      = (const float*)d_in[13];
  const float* btb      = (const float*)d_in[14];
  const float* Wtau_in  = (const float*)d_in[15];
  const float* btau_in  = (const float*)d_in[16];
  const float* Wtau_out = (const float*)d_in[17];
  const float* btau_out = (const float*)d_in[18];
  const float* Wo       = (const float*)d_in[19];
  const float* bo       = (const float*)d_in[20];
  float* out = (float*)d_out;
  float* ws  = (float*)d_ws;

  float* wvec   = ws + WVEC_OFF;
  float* consts = ws + CONST_OFF;
  short* Uth    = (short*)(ws + UTH_OFF);
  short* Utl    = (short*)(ws + UTL_OFF);
  short* xhi    = (short*)(ws + XHI_OFF);
  short* xlo    = (short*)(ws + XLO_OFF);
  short* AOh    = (short*)(ws + XHI_OFF);   // alias: x-splits dead after V-GEMM
  short* AOl    = (short*)(ws + XLO_OFF);
  short* Wvth   = (short*)(ws + WVTH_OFF);
  short* Wvtl   = (short*)(ws + WVTL_OFF);
  short* Woth   = (short*)(ws + WOTH_OFF);
  short* Wotl   = (short*)(ws + WOTL_OFF);
  float* S      = ws + S_OFF;
  short* VT     = (short*)(ws + VT_OFF);

  hipLaunchKernelGGL(k_fold_small, dim3(1), dim3(128), 0, stream,
                     Wphi_in, Wphi_out, bphi_in, bphi_out, Wta, bta, Wtb, btb,
                     Wtau_in, Wtau_out, btau_in, btau_out, wvec);
  hipLaunchKernelGGL(k_fold_U, dim3(96), dim3(256), 0, stream,
                     Wq, bq, Wk, bk, wvec, Uth, Utl, consts);
  hipLaunchKernelGGL(k_split_x, dim3(NTOK*512/8/256), dim3(256), 0, stream, x, xhi, xlo);
  hipLaunchKernelGGL(k_split_w, dim3(8,8,2), dim3(256), 0, stream,
                     Wv, Wo, Wvth, Wvtl, Woth, Wotl);
  hipLaunchKernelGGL(k_S, dim3(NTOK/16), dim3(256), 0, stream, xhi, xlo, Uth, Utl, consts, S);
  k_gemm<1><<<dim3(NTOK/64, 8), dim3(256), 0, stream>>>(xhi, xlo, Wvth, Wvtl, bv, nullptr, VT);
  k_attn<<<dim3(T_/16, B_*H_), dim3(256), 0, stream>>>(S, VT, AOh, AOl);
  k_gemm<0><<<dim3(NTOK/64, 8), dim3(256), 0, stream>>>(AOh, AOl, Woth, Wotl, bo, out, nullptr);
}

// Round 4
// 92.291 us; speedup vs baseline: 3.4439x; 1.1027x over previous
//
#include <hip/hip_runtime.h>
#include <hip/hip_bf16.h>

#define B_  4
#define T_  1024
#define H_  8
#define NTOK (B_*T_)

// workspace float offsets
#define CONST_OFF 512       // 48 (+pad)
#define UTH_OFF   576       // 48x512 bf16 = 12288 float slots
#define UTL_OFF   12864     // 12288
#define XHI_OFF   25152     // 4096x512 bf16 = 1048576 float slots   (aliased by AOh)
#define XLO_OFF   1073728   // 1048576                                (aliased by AOl)
#define WVTH_OFF  2122304   // 512x512 bf16 = 131072 float slots
#define WVTL_OFF  2253376
#define WOTH_OFF  2384448
#define WOTL_OFF  2515520
#define S_OFF     2646592   // 48x4096 fp32 = 196608  (stores EXP2 of plane values)
#define VT_OFF    2843200   // 32x64x1024 bf16 = 1048576
// end 3,891,776 floats ~= 15.6 MB

#define LOG2E 1.4426950408889634f
#define LN2   0.6931471805599453f
#define LN2SQ 0.4804530139182014f

typedef __attribute__((ext_vector_type(4))) float v4f;
typedef __attribute__((ext_vector_type(8))) short v8s;

__device__ inline short bf16r(float f) {
  union { float f; unsigned u; } v; v.f = f;
  return (short)((v.u + 0x7FFFu + ((v.u >> 16) & 1u)) >> 16);
}
__device__ inline float bf16f(short s) {
  union { unsigned u; float f; } v; v.u = ((unsigned)(unsigned short)s) << 16; return v.f;
}

// ---------------------------------------------------------------------------
// Fold small MLP stacks (redundantly per block, trivial) + per-head Wq/Wk
// folds -> Ut hi/lo bf16 [48][512], consts[48].
// s = h*6 + qk*3 + which; phi,c scaled -log2e; tau +log2e.
__global__ __launch_bounds__(256) void k_fold_U(
    const float* __restrict__ Wphi_in, const float* __restrict__ Wphi_out,
    const float* __restrict__ bphi_in, const float* __restrict__ bphi_out,
    const float* __restrict__ Wta, const float* __restrict__ bta,
    const float* __restrict__ Wtb, const float* __restrict__ btb,
    const float* __restrict__ Wtau_in, const float* __restrict__ Wtau_out,
    const float* __restrict__ btau_in, const float* __restrict__ btau_out,
    const float* __restrict__ Wq, const float* __restrict__ bq,
    const float* __restrict__ Wk, const float* __restrict__ bk,
    short* __restrict__ Uth, short* __restrict__ Utl, float* __restrict__ consts) {
  __shared__ float wv[390];
  int t = threadIdx.x;
  if (t < 128) {
    float wp = 0.f;
    for (int j = 0; j < 64; ++j) wp += Wphi_in[t*64+j] * Wphi_out[j];
    float wt = 0.f;
    for (int j = 0; j < 32; ++j) wt += Wtau_in[t*32+j] * Wtau_out[j];
    wv[t]       = wp;
    wv[128 + t] = Wta[t] + Wtb[t];     // T_SCALAR == 1
    wv[256 + t] = wt;
  } else if (t == 128) {
    float bp = bphi_out[0];
    for (int j = 0; j < 64; ++j) bp += bphi_in[j]*Wphi_out[j];
    float bt = btau_out[0];
    for (int j = 0; j < 32; ++j) bt += btau_in[j]*Wtau_out[j];
    wv[384] = bp;
    wv[385] = bta[0] + btb[0];
    wv[386] = bt;
  }
  __syncthreads();
  int idx = blockIdx.x*256 + t;              // 0..24575
  int c = idx & 511;
  int s = idx >> 9;
  int h = s / 6, tt = s % 6;
  int qk = tt / 3;
  int which = tt % 3;
  float scale = (which == 2) ? LOG2E : -LOG2E;
  const float* W = qk ? Wk : Wq;
  const float* wvec = wv + which*128 + qk*64;
  const float* row = W + c*512 + h*64;
  float acc = 0.f;
  #pragma unroll 8
  for (int d = 0; d < 64; ++d) acc += row[d] * wvec[d];
  float v = acc * scale;
  short hi = bf16r(v);
  Uth[s*512 + c] = hi;
  Utl[s*512 + c] = bf16r(v - bf16f(hi));
  if (c == 0) {
    const float* bb = qk ? bk : bq;
    float cs = 0.f;
    for (int d = 0; d < 64; ++d) cs += bb[h*64+d] * wvec[d];
    if (qk == 0) cs += wv[384 + which];
    consts[s] = cs * scale;
  }
}

// ---------------------------------------------------------------------------
// Fused: blocks [0,1024): x fp32 -> bf16 hi/lo (8 elems/thread).
//        blocks [1024,1152): transpose+split Wv/Wo -> [n][k] bf16 hi/lo.
__global__ __launch_bounds__(256) void k_split(const float* __restrict__ x,
                                               const float* __restrict__ Wv, const float* __restrict__ Wo,
                                               short* __restrict__ xh, short* __restrict__ xl,
                                               short* __restrict__ Wvh, short* __restrict__ Wvl,
                                               short* __restrict__ Woh, short* __restrict__ Wol) {
  __shared__ float tile[64][65];
  int bx = blockIdx.x, t = threadIdx.x;
  if (bx < 1024) {
    size_t i = (size_t)(bx*256 + t) * 8;
    float4 a = *(const float4*)(x + i);
    float4 b = *(const float4*)(x + i + 4);
    float vals[8] = {a.x,a.y,a.z,a.w,b.x,b.y,b.z,b.w};
    v8s hi, lo;
    #pragma unroll
    for (int j = 0; j < 8; ++j) {
      short h = bf16r(vals[j]);
      hi[j] = h;
      lo[j] = bf16r(vals[j] - bf16f(h));
    }
    *(v8s*)(xh + i) = hi;
    *(v8s*)(xl + i) = lo;
    return;
  }
  int idx = bx - 1024;              // 0..127
  int z = idx >> 6, rem = idx & 63;
  int k0 = (rem >> 3)*64, n0 = (rem & 7)*64;
  const float* src = z ? Wo : Wv;
  short* dh = z ? Woh : Wvh;
  short* dl = z ? Wol : Wvl;
  int kr = t >> 2, cq = t & 3;
  #pragma unroll
  for (int i = 0; i < 4; ++i) {
    float4 v = *(const float4*)(src + (size_t)(k0+kr)*512 + n0 + cq*16 + i*4);
    tile[kr][cq*16+i*4+0] = v.x; tile[kr][cq*16+i*4+1] = v.y;
    tile[kr][cq*16+i*4+2] = v.z; tile[kr][cq*16+i*4+3] = v.w;
  }
  __syncthreads();
  int nr = t >> 2, ko = t & 3;
  v8s h0,h1,l0,l1;
  #pragma unroll
  for (int i = 0; i < 8; ++i) {
    float a = tile[ko*16+i][nr];
    float b = tile[ko*16+8+i][nr];
    short ha = bf16r(a), hb = bf16r(b);
    h0[i] = ha; l0[i] = bf16r(a - bf16f(ha));
    h1[i] = hb; l1[i] = bf16r(b - bf16f(hb));
  }
  size_t base = (size_t)(n0+nr)*512 + k0 + ko*16;
  *(v8s*)(dh + base) = h0; *(v8s*)(dh + base + 8) = h1;
  *(v8s*)(dl + base) = l0; *(v8s*)(dl + base + 8) = l1;
}

// ---------------------------------------------------------------------------
// E[s][tok] = exp2(x[tok] . Ut[s] + consts[s])  -- pre-exponentiated planes.
__global__ __launch_bounds__(256) void k_S(const short* __restrict__ xh, const short* __restrict__ xl,
                                           const short* __restrict__ Uth, const short* __restrict__ Utl,
                                           const float* __restrict__ consts, float* __restrict__ E) {
  __shared__ float red[3][64][12];
  int tid = threadIdx.x, w = tid >> 6, l = tid & 63, ra = l & 15, kg = l >> 4;
  int mb = blockIdx.x;
  v4f acc[3] = {{0,0,0,0},{0,0,0,0},{0,0,0,0}};
  const short* xa = xh + (size_t)(mb*16+ra)*512;
  const short* xb = xl + (size_t)(mb*16+ra)*512;
  #pragma unroll
  for (int ks = 0; ks < 4; ++ks) {
    int kk = w*128 + ks*32 + kg*8;
    v8s ah = *(const v8s*)(xa + kk);
    v8s al = *(const v8s*)(xb + kk);
    #pragma unroll
    for (int nf = 0; nf < 3; ++nf) {
      v8s bh = *(const v8s*)(Uth + (size_t)(nf*16+ra)*512 + kk);
      v8s bl = *(const v8s*)(Utl + (size_t)(nf*16+ra)*512 + kk);
      acc[nf] = __builtin_amdgcn_mfma_f32_16x16x32_bf16(ah, bh, acc[nf], 0, 0, 0);
      acc[nf] = __builtin_amdgcn_mfma_f32_16x16x32_bf16(ah, bl, acc[nf], 0, 0, 0);
      acc[nf] = __builtin_amdgcn_mfma_f32_16x16x32_bf16(al, bh, acc[nf], 0, 0, 0);
    }
  }
  if (w > 0) {
    #pragma unroll
    for (int nf = 0; nf < 3; ++nf) *(v4f*)&red[w-1][l][nf*4] = acc[nf];
  }
  __syncthreads();
  if (w == 0) {
    #pragma unroll
    for (int p = 0; p < 3; ++p)
      #pragma unroll
      for (int nf = 0; nf < 3; ++nf) acc[nf] += *(const v4f*)&red[p][l][nf*4];
    int t0 = mb*16 + kg*4;
    #pragma unroll
    for (int nf = 0; nf < 3; ++nf) {
      int s = nf*16 + ra;
      float cns = consts[s];
      v4f o;
      #pragma unroll
      for (int c = 0; c < 4; ++c) o[c] = __builtin_amdgcn_exp2f(acc[nf][c] + cns);
      *(v4f*)(E + (size_t)s*NTOK + t0) = o;
    }
  }
}

// ---------------------------------------------------------------------------
// Split-bf16 MFMA GEMM with register prefetch of the next K-tile.
// MODE 0: fp32 C + bias.  MODE 1: bf16 VT[b*8+h][d][t] (BN=64 = one head).
template<int MODE>
__global__ __launch_bounds__(256) void k_gemm(const short* __restrict__ Ah, const short* __restrict__ Al,
                                              const short* __restrict__ Bh, const short* __restrict__ Bl,
                                              const float* __restrict__ bias,
                                              float* __restrict__ C, short* __restrict__ VT) {
  __shared__ short As_h[64][40], As_l[64][40], Bs_h[64][40], Bs_l[64][40];
  int tid = threadIdx.x, l = tid & 63, ra = l & 15, kg = l >> 4;
  int w = tid >> 6, wr = w >> 1, wc = w & 1;
  int mb = blockIdx.x, nb = blockIdx.y;
  v4f acc[2][2] = {};
  int srow = tid >> 2, soct = tid & 3;
  const short* gAh = Ah + (size_t)(mb*64+srow)*512 + soct*8;
  const short* gAl = Al + (size_t)(mb*64+srow)*512 + soct*8;
  const short* gBh = Bh + (size_t)(nb*64+srow)*512 + soct*8;
  const short* gBl = Bl + (size_t)(nb*64+srow)*512 + soct*8;
  v8s sa = *(const v8s*)(gAh);
  v8s sb = *(const v8s*)(gAl);
  v8s sc = *(const v8s*)(gBh);
  v8s sd = *(const v8s*)(gBl);
  for (int k0 = 0; k0 < 512; k0 += 32) {
    __syncthreads();
    *(v8s*)&As_h[srow][soct*8] = sa;
    *(v8s*)&As_l[srow][soct*8] = sb;
    *(v8s*)&Bs_h[srow][soct*8] = sc;
    *(v8s*)&Bs_l[srow][soct*8] = sd;
    if (k0 < 480) {                       // prefetch next K-tile into regs
      sa = *(const v8s*)(gAh + k0 + 32);
      sb = *(const v8s*)(gAl + k0 + 32);
      sc = *(const v8s*)(gBh + k0 + 32);
      sd = *(const v8s*)(gBl + k0 + 32);
    }
    __syncthreads();
    v8s ah[2], al[2], bh[2], bl[2];
    #pragma unroll
    for (int mi = 0; mi < 2; ++mi) {
      int r = wr*32 + mi*16 + ra;
      ah[mi] = *(const v8s*)&As_h[r][kg*8];
      al[mi] = *(const v8s*)&As_l[r][kg*8];
    }
    #pragma unroll
    for (int ni = 0; ni < 2; ++ni) {
      int r = wc*32 + ni*16 + ra;
      bh[ni] = *(const v8s*)&Bs_h[r][kg*8];
      bl[ni] = *(const v8s*)&Bs_l[r][kg*8];
    }
    #pragma unroll
    for (int mi = 0; mi < 2; ++mi)
      #pragma unroll
      for (int ni = 0; ni < 2; ++ni) {
        acc[mi][ni] = __builtin_amdgcn_mfma_f32_16x16x32_bf16(ah[mi], bh[ni], acc[mi][ni], 0, 0, 0);
        acc[mi][ni] = __builtin_amdgcn_mfma_f32_16x16x32_bf16(ah[mi], bl[ni], acc[mi][ni], 0, 0, 0);
        acc[mi][ni] = __builtin_amdgcn_mfma_f32_16x16x32_bf16(al[mi], bh[ni], acc[mi][ni], 0, 0, 0);
      }
  }
  if constexpr (MODE == 0) {
    #pragma unroll
    for (int ni = 0; ni < 2; ++ni) {
      int n = nb*64 + wc*32 + ni*16 + ra;
      float bv_ = bias[n];
      #pragma unroll
      for (int mi = 0; mi < 2; ++mi) {
        int row = mb*64 + wr*32 + mi*16 + kg*4;
        #pragma unroll
        for (int r = 0; r < 4; ++r)
          C[(size_t)(row+r)*512 + n] = acc[mi][ni][r] + bv_;
      }
    }
  } else {
    __shared__ float ldsT[64][65];
    #pragma unroll
    for (int ni = 0; ni < 2; ++ni) {
      int lc = wc*32 + ni*16 + ra;
      float bv_ = bias[nb*64 + lc];
      #pragma unroll
      for (int mi = 0; mi < 2; ++mi) {
        int lr = wr*32 + mi*16 + kg*4;
        #pragma unroll
        for (int r = 0; r < 4; ++r)
          ldsT[lc][lr+r] = acc[mi][ni][r] + bv_;
      }
    }
    __syncthreads();
    int d = tid >> 2, tq = tid & 3;
    v8s h0, h1;
    #pragma unroll
    for (int i = 0; i < 8; ++i) {
      h0[i] = bf16r(ldsT[d][tq*16+i]);
      h1[i] = bf16r(ldsT[d][tq*16+8+i]);
    }
    size_t base = ((size_t)(((mb>>4)*8 + nb)*64 + d))*1024 + (mb&15)*64 + tq*16;
    *(v8s*)(VT + base)     = h0;
    *(v8s*)(VT + base + 8) = h1;
  }
}

// ---------------------------------------------------------------------------
// MFMA flash attention, split-K x4. Planes hold exp2 of the linear forms, so
// per-pair: 3 muls + {rcp, log, exp2, rcp, exp2} (5 trans, was 8).
__global__ __launch_bounds__(256) void k_attn(const float* __restrict__ E,
                                              const short* __restrict__ VT,
                                              short* __restrict__ AOh, short* __restrict__ AOl) {
  __shared__ float red[3][64][20];
  int tid = threadIdx.x, w = tid >> 6, l = tid & 63, ra = l & 15, kg = l >> 4;
  int bh = blockIdx.y, b = bh >> 3, h = bh & 7;
  int q0 = blockIdx.x * 16;
  const float* Eb = E + (size_t)h*6*NTOK + b*T_;
  float eqp = Eb[q0+ra], eqc = Eb[NTOK + q0+ra], eqt = Eb[2*NTOK + q0+ra];
  const float* Ekp = Eb + 3*NTOK;
  const float* Ekc = Eb + 4*NTOK;
  const float* Ekt = Eb + 5*NTOK;
  const short* Vb = VT + (size_t)bh*64*1024 + (size_t)ra*1024;

  v4f acc0 = {0.f,0.f,0.f,0.f}, acc1 = acc0, acc2 = acc0, acc3 = acc0, dacc = acc0;
  v8s ones;
  #pragma unroll
  for (int j = 0; j < 8; ++j) ones[j] = (short)0x3F80;

  #pragma unroll 2
  for (int ks = 0; ks < 8; ++ks) {
    int kk = w*256 + ks*32 + kg*8;
    v4f p0 = *(const v4f*)&Ekp[kk], p1 = *(const v4f*)&Ekp[kk+4];
    v4f c0 = *(const v4f*)&Ekc[kk], c1 = *(const v4f*)&Ekc[kk+4];
    v4f t0 = *(const v4f*)&Ekt[kk], t1 = *(const v4f*)&Ekt[kk+4];
    v8s afrag;
    #pragma unroll
    for (int j = 0; j < 8; ++j) {
      float Ep = (j < 4) ? p0[j] : p1[j-4];
      float Ec = (j < 4) ? c0[j] : c1[j-4];
      float Et = (j < 4) ? t0[j] : t1[j-4];
      float ephi = eqp * Ep;                                   // e^{-a_phi}
      float ec   = eqc * Ec;                                   // e^{-a_c}
      float g    = eqt * Et;                                   // e^{a_tau}
      float ti   = __builtin_amdgcn_rcpf(1.f + ec);            // sigmoid(a_c)
      float t2   = __builtin_amdgcn_logf(1.f + g);             // softplus/ln2
      float z    = 1.f - __builtin_amdgcn_exp2f(-t2 * ti);
      float den  = (1.f + ephi) * fmaf(t2, LN2SQ, 6.93e-7f);   // (1+e)(tau*ln2)
      float p    = __builtin_amdgcn_exp2f(z * __builtin_amdgcn_rcpf(den));
      afrag[j] = bf16r(p);
    }
    v8s b0 = *(const v8s*)(Vb + kk);
    v8s b1 = *(const v8s*)(Vb + 16*1024 + kk);
    v8s b2 = *(const v8s*)(Vb + 32*1024 + kk);
    v8s b3 = *(const v8s*)(Vb + 48*1024 + kk);
    acc0 = __builtin_amdgcn_mfma_f32_16x16x32_bf16(afrag, b0, acc0, 0, 0, 0);
    acc1 = __builtin_amdgcn_mfma_f32_16x16x32_bf16(afrag, b1, acc1, 0, 0, 0);
    acc2 = __builtin_amdgcn_mfma_f32_16x16x32_bf16(afrag, b2, acc2, 0, 0, 0);
    acc3 = __builtin_amdgcn_mfma_f32_16x16x32_bf16(afrag, b3, acc3, 0, 0, 0);
    dacc = __builtin_amdgcn_mfma_f32_16x16x32_bf16(afrag, ones, dacc, 0, 0, 0);
  }

  if (w > 0) {
    float* rp = &red[w-1][l][0];
    *(v4f*)(rp)      = acc0;
    *(v4f*)(rp + 4)  = acc1;
    *(v4f*)(rp + 8)  = acc2;
    *(v4f*)(rp + 12) = acc3;
    *(v4f*)(rp + 16) = dacc;
  }
  __syncthreads();
  if (w == 0) {
    #pragma unroll
    for (int p = 0; p < 3; ++p) {
      const float* rp = &red[p][l][0];
      acc0 += *(const v4f*)(rp);
      acc1 += *(const v4f*)(rp + 4);
      acc2 += *(const v4f*)(rp + 8);
      acc3 += *(const v4f*)(rp + 12);
      dacc += *(const v4f*)(rp + 16);
    }
    size_t obase = ((size_t)(b*T_ + q0 + kg*4))*512 + h*64 + ra;
    #pragma unroll
    for (int r = 0; r < 4; ++r) {
      float inv = __builtin_amdgcn_rcpf(dacc[r]);
      size_t o = obase + (size_t)r*512;
      float v0 = acc0[r]*inv, v1 = acc1[r]*inv, v2 = acc2[r]*inv, v3 = acc3[r]*inv;
      short h0 = bf16r(v0), h1 = bf16r(v1), h2 = bf16r(v2), h3 = bf16r(v3);
      AOh[o+0]  = h0; AOl[o+0]  = bf16r(v0 - bf16f(h0));
      AOh[o+16] = h1; AOl[o+16] = bf16r(v1 - bf16f(h1));
      AOh[o+32] = h2; AOl[o+32] = bf16r(v2 - bf16f(h2));
      AOh[o+48] = h3; AOl[o+48] = bf16r(v3 - bf16f(h3));
    }
  }
}

// ---------------------------------------------------------------------------
extern "C" void kernel_launch(void* const* d_in, const int* in_sizes, int n_in,
                              void* d_out, int out_size, void* d_ws, size_t ws_size,
                              hipStream_t stream) {
  (void)in_sizes; (void)n_in; (void)out_size; (void)ws_size;
  const float* x        = (const float*)d_in[0];
  const float* Wq       = (const float*)d_in[1];
  const float* bq       = (const float*)d_in[2];
  const float* Wk       = (const float*)d_in[3];
  const float* bk       = (const float*)d_in[4];
  const float* Wv       = (const float*)d_in[5];
  const float* bv       = (const float*)d_in[6];
  const float* Wphi_in  = (const float*)d_in[7];
  const float* bphi_in  = (const float*)d_in[8];
  const float* Wphi_out = (const float*)d_in[9];
  const float* bphi_out = (const float*)d_in[10];
  const float* Wta      = (const float*)d_in[11];
  const float* bta      = (const float*)d_in[12];
  const float* Wtb      = (const float*)d_in[13];
  const float* btb      = (const float*)d_in[14];
  const float* Wtau_in  = (const float*)d_in[15];
  const float* btau_in  = (const float*)d_in[16];
  const float* Wtau_out = (const float*)d_in[17];
  const float* btau_out = (const float*)d_in[18];
  const float* Wo       = (const float*)d_in[19];
  const float* bo       = (const float*)d_in[20];
  float* out = (float*)d_out;
  float* ws  = (float*)d_ws;

  float* consts = ws + CONST_OFF;
  short* Uth    = (short*)(ws + UTH_OFF);
  short* Utl    = (short*)(ws + UTL_OFF);
  short* xhi    = (short*)(ws + XHI_OFF);
  short* xlo    = (short*)(ws + XLO_OFF);
  short* AOh    = (short*)(ws + XHI_OFF);   // alias: x-splits dead after V-GEMM
  short* AOl    = (short*)(ws + XLO_OFF);
  short* Wvth   = (short*)(ws + WVTH_OFF);
  short* Wvtl   = (short*)(ws + WVTL_OFF);
  short* Woth   = (short*)(ws + WOTH_OFF);
  short* Wotl   = (short*)(ws + WOTL_OFF);
  float* E      = ws + S_OFF;
  short* VT     = (short*)(ws + VT_OFF);

  hipLaunchKernelGGL(k_fold_U, dim3(96), dim3(256), 0, stream,
                     Wphi_in, Wphi_out, bphi_in, bphi_out, Wta, bta, Wtb, btb,
                     Wtau_in, Wtau_out, btau_in, btau_out,
                     Wq, bq, Wk, bk, Uth, Utl, consts);
  hipLaunchKernelGGL(k_split, dim3(1152), dim3(256), 0, stream,
                     x, Wv, Wo, xhi, xlo, Wvth, Wvtl, Woth, Wotl);
  hipLaunchKernelGGL(k_S, dim3(NTOK/16), dim3(256), 0, stream, xhi, xlo, Uth, Utl, consts, E);
  k_gemm<1><<<dim3(NTOK/64, 8), dim3(256), 0, stream>>>(xhi, xlo, Wvth, Wvtl, bv, nullptr, VT);
  k_attn<<<dim3(T_/16, B_*H_), dim3(256), 0, stream>>>(E, VT, AOh, AOl);
  k_gemm<0><<<dim3(NTOK/64, 8), dim3(256), 0, stream>>>(AOh, AOl, Woth, Wotl, bo, out, nullptr);
}

// Round 5
// 69.564 us; speedup vs baseline: 4.5690x; 1.3267x over previous
//
#include <hip/hip_runtime.h>
#include <hip/hip_bf16.h>

#define B_  4
#define T_  1024
#define H_  8
#define NTOK (B_*T_)

// workspace float offsets
#define CONST_OFF 512       // 48 (+pad)
#define UTH_OFF   576       // 48x512 bf16 = 12288 float slots
#define UTL_OFF   12864     // 12288
#define XHI_OFF   25152     // 4096x512 bf16 = 1048576 float slots   (aliased by AOh)
#define XLO_OFF   1073728   // 1048576                                (aliased by AOl)
#define WVTH_OFF  2122304   // 512x512 bf16 = 131072 float slots
#define WVTL_OFF  2253376
#define WOTH_OFF  2384448
#define WOTL_OFF  2515520
#define S_OFF     2646592   // 48x4096 fp32 (EXP2 of plane values)
#define VT_OFF    2843200   // 32x64x1024 bf16
// end 3,891,776 floats ~= 15.6 MB

#define LOG2E 1.4426950408889634f
#define LN2SQ 0.4804530139182014f

typedef __attribute__((ext_vector_type(4))) float v4f;
typedef __attribute__((ext_vector_type(8))) short v8s;

__device__ inline short bf16r(float f) {
  union { float f; unsigned u; } v; v.f = f;
  return (short)((v.u + 0x7FFFu + ((v.u >> 16) & 1u)) >> 16);
}
__device__ inline float bf16f(short s) {
  union { unsigned u; float f; } v; v.u = ((unsigned)(unsigned short)s) << 16; return v.f;
}
__device__ inline unsigned cvt_pk_bf16(float lo, float hi) {
  unsigned r;
  asm("v_cvt_pk_bf16_f32 %0, %1, %2" : "=v"(r) : "v"(lo), "v"(hi));
  return r;
}

// ---------------------------------------------------------------------------
// Fused prep: [0,96) fold Wq/Wk against MLP-stack folds -> Ut hi/lo + consts;
// [96,1120) x fp32 -> bf16 hi/lo; [1120,1248) transpose+split Wv/Wo.
__global__ __launch_bounds__(256) void k_prep(
    const float* __restrict__ Wphi_in, const float* __restrict__ Wphi_out,
    const float* __restrict__ bphi_in, const float* __restrict__ bphi_out,
    const float* __restrict__ Wta, const float* __restrict__ bta,
    const float* __restrict__ Wtb, const float* __restrict__ btb,
    const float* __restrict__ Wtau_in, const float* __restrict__ Wtau_out,
    const float* __restrict__ btau_in, const float* __restrict__ btau_out,
    const float* __restrict__ Wq, const float* __restrict__ bq,
    const float* __restrict__ Wk, const float* __restrict__ bk,
    const float* __restrict__ x, const float* __restrict__ Wv, const float* __restrict__ Wo,
    short* __restrict__ Uth, short* __restrict__ Utl, float* __restrict__ consts,
    short* __restrict__ xh, short* __restrict__ xl,
    short* __restrict__ Wvh, short* __restrict__ Wvl,
    short* __restrict__ Woh, short* __restrict__ Wol) {
  __shared__ float wv[390];
  __shared__ float tile[64][65];
  int bx = blockIdx.x, t = threadIdx.x;
  if (bx < 96) {
    if (t < 128) {
      float wp = 0.f;
      for (int j = 0; j < 64; ++j) wp += Wphi_in[t*64+j] * Wphi_out[j];
      float wt = 0.f;
      for (int j = 0; j < 32; ++j) wt += Wtau_in[t*32+j] * Wtau_out[j];
      wv[t]       = wp;
      wv[128 + t] = Wta[t] + Wtb[t];     // T_SCALAR == 1
      wv[256 + t] = wt;
    } else if (t == 128) {
      float bp = bphi_out[0];
      for (int j = 0; j < 64; ++j) bp += bphi_in[j]*Wphi_out[j];
      float bt = btau_out[0];
      for (int j = 0; j < 32; ++j) bt += btau_in[j]*Wtau_out[j];
      wv[384] = bp;
      wv[385] = bta[0] + btb[0];
      wv[386] = bt;
    }
    __syncthreads();
    int idx = bx*256 + t;              // 0..24575
    int c = idx & 511;
    int s = idx >> 9;
    int h = s / 6, tt = s % 6;
    int qk = tt / 3;
    int which = tt % 3;
    float scale = (which == 2) ? LOG2E : -LOG2E;
    const float* W = qk ? Wk : Wq;
    const float* wvec = wv + which*128 + qk*64;
    const float* row = W + c*512 + h*64;
    float acc = 0.f;
    #pragma unroll 8
    for (int d = 0; d < 64; ++d) acc += row[d] * wvec[d];
    float v = acc * scale;
    short hi = bf16r(v);
    Uth[s*512 + c] = hi;
    Utl[s*512 + c] = bf16r(v - bf16f(hi));
    if (c == 0) {
      const float* bb = qk ? bk : bq;
      float cs = 0.f;
      for (int d = 0; d < 64; ++d) cs += bb[h*64+d] * wvec[d];
      if (qk == 0) cs += wv[384 + which];
      consts[s] = cs * scale;
    }
    return;
  }
  if (bx < 1120) {
    size_t i = (size_t)((bx-96)*256 + t) * 8;
    float4 a = *(const float4*)(x + i);
    float4 b = *(const float4*)(x + i + 4);
    float vals[8] = {a.x,a.y,a.z,a.w,b.x,b.y,b.z,b.w};
    v8s hi, lo;
    #pragma unroll
    for (int j = 0; j < 8; ++j) {
      short h = bf16r(vals[j]);
      hi[j] = h;
      lo[j] = bf16r(vals[j] - bf16f(h));
    }
    *(v8s*)(xh + i) = hi;
    *(v8s*)(xl + i) = lo;
    return;
  }
  int idx = bx - 1120;              // 0..127
  int z = idx >> 6, rem = idx & 63;
  int k0 = (rem >> 3)*64, n0 = (rem & 7)*64;
  const float* src = z ? Wo : Wv;
  short* dh = z ? Woh : Wvh;
  short* dl = z ? Wol : Wvl;
  int kr = t >> 2, cq = t & 3;
  #pragma unroll
  for (int i = 0; i < 4; ++i) {
    float4 v = *(const float4*)(src + (size_t)(k0+kr)*512 + n0 + cq*16 + i*4);
    tile[kr][cq*16+i*4+0] = v.x; tile[kr][cq*16+i*4+1] = v.y;
    tile[kr][cq*16+i*4+2] = v.z; tile[kr][cq*16+i*4+3] = v.w;
  }
  __syncthreads();
  int nr = t >> 2, ko = t & 3;
  v8s h0,h1,l0,l1;
  #pragma unroll
  for (int i = 0; i < 8; ++i) {
    float a = tile[ko*16+i][nr];
    float b = tile[ko*16+8+i][nr];
    short ha = bf16r(a), hb = bf16r(b);
    h0[i] = ha; l0[i] = bf16r(a - bf16f(ha));
    h1[i] = hb; l1[i] = bf16r(b - bf16f(hb));
  }
  size_t base = (size_t)(n0+nr)*512 + k0 + ko*16;
  *(v8s*)(dh + base) = h0; *(v8s*)(dh + base + 8) = h1;
  *(v8s*)(dl + base) = l0; *(v8s*)(dl + base + 8) = l1;
}

// ---------------------------------------------------------------------------
// Split-bf16 MFMA GEMM body (Ah*Bh + Ah*Bl + Al*Bh) with register prefetch.
// MODE 0: fp32 C + bias.  MODE 1: bf16 VT[b*8+h][d][t] (BN=64 = one head).
template<int MODE>
__device__ __forceinline__ void gemm_body(char* smem, int mb, int nb,
    const short* __restrict__ Ah, const short* __restrict__ Al,
    const short* __restrict__ Bh, const short* __restrict__ Bl,
    const float* __restrict__ bias, float* __restrict__ C, short* __restrict__ VT) {
  short (*As_h)[40] = (short(*)[40])(smem);
  short (*As_l)[40] = (short(*)[40])(smem + 5120);
  short (*Bs_h)[40] = (short(*)[40])(smem + 10240);
  short (*Bs_l)[40] = (short(*)[40])(smem + 15360);
  int tid = threadIdx.x, l = tid & 63, ra = l & 15, kg = l >> 4;
  int w = tid >> 6, wr = w >> 1, wc = w & 1;
  v4f acc[2][2] = {};
  int srow = tid >> 2, soct = tid & 3;
  const short* gAh = Ah + (size_t)(mb*64+srow)*512 + soct*8;
  const short* gAl = Al + (size_t)(mb*64+srow)*512 + soct*8;
  const short* gBh = Bh + (size_t)(nb*64+srow)*512 + soct*8;
  const short* gBl = Bl + (size_t)(nb*64+srow)*512 + soct*8;
  v8s sa = *(const v8s*)(gAh);
  v8s sb = *(const v8s*)(gAl);
  v8s sc = *(const v8s*)(gBh);
  v8s sd = *(const v8s*)(gBl);
  for (int k0 = 0; k0 < 512; k0 += 32) {
    __syncthreads();
    *(v8s*)&As_h[srow][soct*8] = sa;
    *(v8s*)&As_l[srow][soct*8] = sb;
    *(v8s*)&Bs_h[srow][soct*8] = sc;
    *(v8s*)&Bs_l[srow][soct*8] = sd;
    if (k0 < 480) {                       // prefetch next K-tile into regs
      sa = *(const v8s*)(gAh + k0 + 32);
      sb = *(const v8s*)(gAl + k0 + 32);
      sc = *(const v8s*)(gBh + k0 + 32);
      sd = *(const v8s*)(gBl + k0 + 32);
    }
    __syncthreads();
    v8s ah[2], al[2], bh[2], bl[2];
    #pragma unroll
    for (int mi = 0; mi < 2; ++mi) {
      int r = wr*32 + mi*16 + ra;
      ah[mi] = *(const v8s*)&As_h[r][kg*8];
      al[mi] = *(const v8s*)&As_l[r][kg*8];
    }
    #pragma unroll
    for (int ni = 0; ni < 2; ++ni) {
      int r = wc*32 + ni*16 + ra;
      bh[ni] = *(const v8s*)&Bs_h[r][kg*8];
      bl[ni] = *(const v8s*)&Bs_l[r][kg*8];
    }
    #pragma unroll
    for (int mi = 0; mi < 2; ++mi)
      #pragma unroll
      for (int ni = 0; ni < 2; ++ni) {
        acc[mi][ni] = __builtin_amdgcn_mfma_f32_16x16x32_bf16(ah[mi], bh[ni], acc[mi][ni], 0, 0, 0);
        acc[mi][ni] = __builtin_amdgcn_mfma_f32_16x16x32_bf16(ah[mi], bl[ni], acc[mi][ni], 0, 0, 0);
        acc[mi][ni] = __builtin_amdgcn_mfma_f32_16x16x32_bf16(al[mi], bh[ni], acc[mi][ni], 0, 0, 0);
      }
  }
  if constexpr (MODE == 0) {
    #pragma unroll
    for (int ni = 0; ni < 2; ++ni) {
      int n = nb*64 + wc*32 + ni*16 + ra;
      float bv_ = bias[n];
      #pragma unroll
      for (int mi = 0; mi < 2; ++mi) {
        int row = mb*64 + wr*32 + mi*16 + kg*4;
        #pragma unroll
        for (int r = 0; r < 4; ++r)
          C[(size_t)(row+r)*512 + n] = acc[mi][ni][r] + bv_;
      }
    }
  } else {
    __syncthreads();                      // As/Bs reads done; alias ldsT
    float (*ldsT)[65] = (float(*)[65])(smem);
    #pragma unroll
    for (int ni = 0; ni < 2; ++ni) {
      int lc = wc*32 + ni*16 + ra;
      float bv_ = bias[nb*64 + lc];
      #pragma unroll
      for (int mi = 0; mi < 2; ++mi) {
        int lr = wr*32 + mi*16 + kg*4;
        #pragma unroll
        for (int r = 0; r < 4; ++r)
          ldsT[lc][lr+r] = acc[mi][ni][r] + bv_;
      }
    }
    __syncthreads();
    int d = tid >> 2, tq = tid & 3;
    v8s h0, h1;
    #pragma unroll
    for (int i = 0; i < 8; ++i) {
      h0[i] = bf16r(ldsT[d][tq*16+i]);
      h1[i] = bf16r(ldsT[d][tq*16+8+i]);
    }
    size_t base = ((size_t)(((mb>>4)*8 + nb)*64 + d))*1024 + (mb&15)*64 + tq*16;
    *(v8s*)(VT + base)     = h0;
    *(v8s*)(VT + base + 8) = h1;
  }
}

// ---------------------------------------------------------------------------
// E[s][tok] = exp2(x . Ut[s] + consts[s]) via split-bf16 MFMA; 16 rows/block.
__device__ __forceinline__ void S_body(char* smem, int mb,
    const short* __restrict__ xh, const short* __restrict__ xl,
    const short* __restrict__ Uth, const short* __restrict__ Utl,
    const float* __restrict__ consts, float* __restrict__ E) {
  float* red = (float*)smem;            // [3][64][12]
  int tid = threadIdx.x, w = tid >> 6, l = tid & 63, ra = l & 15, kg = l >> 4;
  v4f acc[3] = {{0,0,0,0},{0,0,0,0},{0,0,0,0}};
  const short* xa = xh + (size_t)(mb*16+ra)*512;
  const short* xb = xl + (size_t)(mb*16+ra)*512;
  #pragma unroll
  for (int ks = 0; ks < 4; ++ks) {
    int kk = w*128 + ks*32 + kg*8;
    v8s ah = *(const v8s*)(xa + kk);
    v8s al = *(const v8s*)(xb + kk);
    #pragma unroll
    for (int nf = 0; nf < 3; ++nf) {
      v8s bh = *(const v8s*)(Uth + (size_t)(nf*16+ra)*512 + kk);
      v8s bl = *(const v8s*)(Utl + (size_t)(nf*16+ra)*512 + kk);
      acc[nf] = __builtin_amdgcn_mfma_f32_16x16x32_bf16(ah, bh, acc[nf], 0, 0, 0);
      acc[nf] = __builtin_amdgcn_mfma_f32_16x16x32_bf16(ah, bl, acc[nf], 0, 0, 0);
      acc[nf] = __builtin_amdgcn_mfma_f32_16x16x32_bf16(al, bh, acc[nf], 0, 0, 0);
    }
  }
  if (w > 0) {
    #pragma unroll
    for (int nf = 0; nf < 3; ++nf) *(v4f*)(red + ((w-1)*64 + l)*12 + nf*4) = acc[nf];
  }
  __syncthreads();
  if (w == 0) {
    #pragma unroll
    for (int p = 0; p < 3; ++p)
      #pragma unroll
      for (int nf = 0; nf < 3; ++nf) acc[nf] += *(const v4f*)(red + (p*64 + l)*12 + nf*4);
    int t0 = mb*16 + kg*4;
    #pragma unroll
    for (int nf = 0; nf < 3; ++nf) {
      int s = nf*16 + ra;
      float cns = consts[s];
      v4f o;
      #pragma unroll
      for (int c = 0; c < 4; ++c) o[c] = __builtin_amdgcn_exp2f(acc[nf][c] + cns);
      *(v4f*)(E + (size_t)s*NTOK + t0) = o;
    }
  }
}

// Fused mid stage: [0,256) = S/E planes; [256,768) = V-GEMM (MODE 1).
__global__ __launch_bounds__(256) void k_mid(
    const short* __restrict__ xh, const short* __restrict__ xl,
    const short* __restrict__ Uth, const short* __restrict__ Utl,
    const float* __restrict__ consts, float* __restrict__ E,
    const short* __restrict__ Wvh, const short* __restrict__ Wvl,
    const float* __restrict__ bv, short* __restrict__ VT) {
  __shared__ __align__(16) char smem[20480];
  int bx = blockIdx.x;
  if (bx < 256) {
    S_body(smem, bx, xh, xl, Uth, Utl, consts, E);
  } else {
    int i = bx - 256;
    gemm_body<1>(smem, i >> 3, i & 7, xh, xl, Wvh, Wvl, bv, nullptr, VT);
  }
}

// ---------------------------------------------------------------------------
__global__ __launch_bounds__(256) void k_out(
    const short* __restrict__ Ah, const short* __restrict__ Al,
    const short* __restrict__ Bh, const short* __restrict__ Bl,
    const float* __restrict__ bias, float* __restrict__ C) {
  __shared__ __align__(16) char smem[20480];
  gemm_body<0>(smem, blockIdx.x, blockIdx.y, Ah, Al, Bh, Bl, bias, C, nullptr);
}

// ---------------------------------------------------------------------------
// MFMA flash attention: 32 q-rows/block (2 A-frags), 4 B-frags reused across
// both A-frags (halves V traffic/logit), split-K x4, LDS combine.
__global__ __launch_bounds__(256) void k_attn(const float* __restrict__ E,
                                              const short* __restrict__ VT,
                                              short* __restrict__ AOh, short* __restrict__ AOl) {
  __shared__ float red[3][64][40];
  int tid = threadIdx.x, w = tid >> 6, l = tid & 63, ra = l & 15, kg = l >> 4;
  int bh = blockIdx.y, b = bh >> 3, h = bh & 7;
  int q0 = blockIdx.x * 32;
  const float* Eb = E + (size_t)h*6*NTOK + b*T_;
  float eqp[2], eqc[2], eqt[2];
  #pragma unroll
  for (int ai = 0; ai < 2; ++ai) {
    eqp[ai] = Eb[q0 + ai*16 + ra];
    eqc[ai] = Eb[NTOK + q0 + ai*16 + ra];
    eqt[ai] = Eb[2*NTOK + q0 + ai*16 + ra];
  }
  const float* Ekp = Eb + 3*NTOK;
  const float* Ekc = Eb + 4*NTOK;
  const float* Ekt = Eb + 5*NTOK;
  const short* Vb = VT + (size_t)bh*64*1024 + (size_t)ra*1024;

  v4f acc[2][4] = {};
  v4f dacc[2] = {};
  v8s ones;
  #pragma unroll
  for (int j = 0; j < 8; ++j) ones[j] = (short)0x3F80;

  #pragma unroll 2
  for (int ks = 0; ks < 8; ++ks) {
    int kk = w*256 + ks*32 + kg*8;
    v4f p0 = *(const v4f*)&Ekp[kk], p1 = *(const v4f*)&Ekp[kk+4];
    v4f c0 = *(const v4f*)&Ekc[kk], c1 = *(const v4f*)&Ekc[kk+4];
    v4f t0 = *(const v4f*)&Ekt[kk], t1 = *(const v4f*)&Ekt[kk+4];
    v8s bfr[4];
    #pragma unroll
    for (int ni = 0; ni < 4; ++ni) bfr[ni] = *(const v8s*)(Vb + (size_t)ni*16*1024 + kk);
    #pragma unroll
    for (int ai = 0; ai < 2; ++ai) {
      float p8[8];
      #pragma unroll
      for (int j = 0; j < 8; ++j) {
        float Ep = (j < 4) ? p0[j] : p1[j-4];
        float Ec = (j < 4) ? c0[j] : c1[j-4];
        float Et = (j < 4) ? t0[j] : t1[j-4];
        float ephi = eqp[ai] * Ep;                               // e^{-a_phi}
        float ec   = eqc[ai] * Ec;                               // e^{-a_c}
        float g    = eqt[ai] * Et;                               // e^{a_tau}
        float ti   = __builtin_amdgcn_rcpf(1.f + ec);            // sigmoid(a_c)
        float t2   = __builtin_amdgcn_logf(1.f + g);             // softplus/ln2
        float z    = 1.f - __builtin_amdgcn_exp2f(-t2 * ti);
        float den  = (1.f + ephi) * fmaf(t2, LN2SQ, 6.93e-7f);
        p8[j] = __builtin_amdgcn_exp2f(z * __builtin_amdgcn_rcpf(den));
      }
      union { unsigned u[4]; v8s s; } af;
      af.u[0] = cvt_pk_bf16(p8[0], p8[1]);
      af.u[1] = cvt_pk_bf16(p8[2], p8[3]);
      af.u[2] = cvt_pk_bf16(p8[4], p8[5]);
      af.u[3] = cvt_pk_bf16(p8[6], p8[7]);
      v8s afrag = af.s;
      #pragma unroll
      for (int ni = 0; ni < 4; ++ni)
        acc[ai][ni] = __builtin_amdgcn_mfma_f32_16x16x32_bf16(afrag, bfr[ni], acc[ai][ni], 0, 0, 0);
      dacc[ai] = __builtin_amdgcn_mfma_f32_16x16x32_bf16(afrag, ones, dacc[ai], 0, 0, 0);
    }
  }

  if (w > 0) {
    float* rp = &red[w-1][l][0];
    #pragma unroll
    for (int ai = 0; ai < 2; ++ai) {
      #pragma unroll
      for (int ni = 0; ni < 4; ++ni) *(v4f*)(rp + ai*16 + ni*4) = acc[ai][ni];
      *(v4f*)(rp + 32 + ai*4) = dacc[ai];
    }
  }
  __syncthreads();
  if (w == 0) {
    #pragma unroll
    for (int p = 0; p < 3; ++p) {
      const float* rp = &red[p][l][0];
      #pragma unroll
      for (int ai = 0; ai < 2; ++ai) {
        #pragma unroll
        for (int ni = 0; ni < 4; ++ni) acc[ai][ni] += *(const v4f*)(rp + ai*16 + ni*4);
        dacc[ai] += *(const v4f*)(rp + 32 + ai*4);
      }
    }
    #pragma unroll
    for (int ai = 0; ai < 2; ++ai) {
      size_t qb = (size_t)(b*T_ + q0 + ai*16 + kg*4);
      #pragma unroll
      for (int r = 0; r < 4; ++r) {
        float inv = __builtin_amdgcn_rcpf(dacc[ai][r]);
        size_t o = (qb + r)*512 + h*64 + ra;
        #pragma unroll
        for (int ni = 0; ni < 4; ++ni) {
          float v = acc[ai][ni][r] * inv;
          short hh = bf16r(v);
          AOh[o + ni*16] = hh;
          AOl[o + ni*16] = bf16r(v - bf16f(hh));
        }
      }
    }
  }
}

// ---------------------------------------------------------------------------
extern "C" void kernel_launch(void* const* d_in, const int* in_sizes, int n_in,
                              void* d_out, int out_size, void* d_ws, size_t ws_size,
                              hipStream_t stream) {
  (void)in_sizes; (void)n_in; (void)out_size; (void)ws_size;
  const float* x        = (const float*)d_in[0];
  const float* Wq       = (const float*)d_in[1];
  const float* bq       = (const float*)d_in[2];
  const float* Wk       = (const float*)d_in[3];
  const float* bk       = (const float*)d_in[4];
  const float* Wv       = (const float*)d_in[5];
  const float* bv       = (const float*)d_in[6];
  const float* Wphi_in  = (const float*)d_in[7];
  const float* bphi_in  = (const float*)d_in[8];
  const float* Wphi_out = (const float*)d_in[9];
  const float* bphi_out = (const float*)d_in[10];
  const float* Wta      = (const float*)d_in[11];
  const float* bta      = (const float*)d_in[12];
  const float* Wtb      = (const float*)d_in[13];
  const float* btb      = (const float*)d_in[14];
  const float* Wtau_in  = (const float*)d_in[15];
  const float* btau_in  = (const float*)d_in[16];
  const float* Wtau_out = (const float*)d_in[17];
  const float* btau_out = (const float*)d_in[18];
  const float* Wo       = (const float*)d_in[19];
  const float* bo       = (const float*)d_in[20];
  float* out = (float*)d_out;
  float* ws  = (float*)d_ws;

  float* consts = ws + CONST_OFF;
  short* Uth    = (short*)(ws + UTH_OFF);
  short* Utl    = (short*)(ws + UTL_OFF);
  short* xhi    = (short*)(ws + XHI_OFF);
  short* xlo    = (short*)(ws + XLO_OFF);
  short* AOh    = (short*)(ws + XHI_OFF);   // alias: x-splits dead after V-GEMM
  short* AOl    = (short*)(ws + XLO_OFF);
  short* Wvth   = (short*)(ws + WVTH_OFF);
  short* Wvtl   = (short*)(ws + WVTL_OFF);
  short* Woth   = (short*)(ws + WOTH_OFF);
  short* Wotl   = (short*)(ws + WOTL_OFF);
  float* E      = ws + S_OFF;
  short* VT     = (short*)(ws + VT_OFF);

  hipLaunchKernelGGL(k_prep, dim3(1248), dim3(256), 0, stream,
                     Wphi_in, Wphi_out, bphi_in, bphi_out, Wta, bta, Wtb, btb,
                     Wtau_in, Wtau_out, btau_in, btau_out,
                     Wq, bq, Wk, bk, x, Wv, Wo,
                     Uth, Utl, consts, xhi, xlo, Wvth, Wvtl, Woth, Wotl);
  hipLaunchKernelGGL(k_mid, dim3(768), dim3(256), 0, stream,
                     xhi, xlo, Uth, Utl, consts, E, Wvth, Wvtl, bv, VT);
  hipLaunchKernelGGL(k_attn, dim3(T_/32, B_*H_), dim3(256), 0, stream, E, VT, AOh, AOl);
  hipLaunchKernelGGL(k_out, dim3(NTOK/64, 8), dim3(256), 0, stream,
                     AOh, AOl, Woth, Wotl, bo, out);
}